// Round 1
// baseline (4692.303 us; speedup 1.0000x reference)
//
#include <hip/hip_runtime.h>
#include <hip/hip_bf16.h>
#include <cstdint>

#define H_  1024
#define NH_ 16
#define DH_ 64
#define I_  4096
#define E_  8
#define B_  2
#define S_  2048
#define N_  4096        // B_*S_
#define LN_EPS 1e-12f

// ---------- helpers ----------
__device__ __forceinline__ float bf2f(unsigned short u) {
  union { unsigned int i; float f; } c; c.i = ((unsigned int)u) << 16; return c.f;
}
__device__ __forceinline__ unsigned short f2bf(float f) {
  __hip_bfloat16 h = __float2bfloat16(f);
  return *reinterpret_cast<unsigned short*>(&h);
}
__device__ __forceinline__ float4 load4f(const float* p) { return *(const float4*)p; }
__device__ __forceinline__ float4 load4f(const __hip_bfloat16* p) {
  const ushort4 u = *(const ushort4*)p;
  float4 r; r.x = bf2f(u.x); r.y = bf2f(u.y); r.z = bf2f(u.z); r.w = bf2f(u.w); return r;
}
__device__ __forceinline__ float gelu_f(float x) {
  return 0.5f * x * (1.0f + erff(x * 0.70710678118f));   // exact GELU
}

// ---------- generic fp32 GEMM: C = A*W + bias ----------
// A [M,K] row-major (fp32 or bf16), W [K,Nn] row-major fp32. 64x64 tile, BK=16.
template <typename TA>
__global__ __launch_bounds__(256) void gemm_bias_kernel(
    const TA* __restrict__ A, const float* __restrict__ W,
    const float* __restrict__ bias, float* __restrict__ C,
    int M, int K, int Nn)
{
  __shared__ float As[16][64];   // [k][m]
  __shared__ float Bs[16][68];   // [k][n] padded
  const int tid = threadIdx.x;
  const int tx = tid & 15, ty = tid >> 4;
  const int m0 = blockIdx.y << 6, n0 = blockIdx.x << 6;
  const int lm = tid & 63, lk = (tid >> 6) << 2;     // A tile load: row lm, k lk..lk+3
  const int bk = tid >> 4, bn = (tid & 15) << 2;     // B tile load: k bk, col bn..bn+3
  float acc[4][4] = {{0.f}};
  for (int kt = 0; kt < K; kt += 16) {
    const float4 a4 = load4f(&A[(size_t)(m0 + lm) * K + kt + lk]);
    const float4 b4 = *(const float4*)&W[(size_t)(kt + bk) * Nn + n0 + bn];
    __syncthreads();
    As[lk + 0][lm] = a4.x; As[lk + 1][lm] = a4.y;
    As[lk + 2][lm] = a4.z; As[lk + 3][lm] = a4.w;
    *(float4*)&Bs[bk][bn] = b4;
    __syncthreads();
#pragma unroll
    for (int k2 = 0; k2 < 16; ++k2) {
      const float a0 = As[k2][ty], a1 = As[k2][ty + 16],
                  a2 = As[k2][ty + 32], a3 = As[k2][ty + 48];
      const float4 b = *(const float4*)&Bs[k2][tx << 2];
      acc[0][0] += a0 * b.x; acc[0][1] += a0 * b.y; acc[0][2] += a0 * b.z; acc[0][3] += a0 * b.w;
      acc[1][0] += a1 * b.x; acc[1][1] += a1 * b.y; acc[1][2] += a1 * b.z; acc[1][3] += a1 * b.w;
      acc[2][0] += a2 * b.x; acc[2][1] += a2 * b.y; acc[2][2] += a2 * b.z; acc[2][3] += a2 * b.w;
      acc[3][0] += a3 * b.x; acc[3][1] += a3 * b.y; acc[3][2] += a3 * b.z; acc[3][3] += a3 * b.w;
    }
  }
  const float4 bias4 = *(const float4*)&bias[n0 + (tx << 2)];
#pragma unroll
  for (int i = 0; i < 4; ++i) {
    const int row = m0 + ty + (i << 4);
    float4 v;
    v.x = acc[i][0] + bias4.x; v.y = acc[i][1] + bias4.y;
    v.z = acc[i][2] + bias4.z; v.w = acc[i][3] + bias4.w;
    *(float4*)&C[(size_t)row * Nn + n0 + (tx << 2)] = v;
  }
}

// ---------- attention: one wave per q-row, 4 keys/iter, online softmax ----------
__global__ __launch_bounds__(256) void attn_kernel(
    const float* __restrict__ q, const float* __restrict__ k,
    const float* __restrict__ v, float* __restrict__ ctx)
{
  const int wid  = (blockIdx.x << 2) + (threadIdx.x >> 6);
  const int lane = threadIdx.x & 63;
  const int lq = lane & 15, kg = lane >> 4;
  const int b  = wid >> 15;            // / (NH_*S_)
  const int h  = (wid >> 11) & 15;
  const int qi = wid & 2047;
  const size_t qoff = ((size_t)(b * S_ + qi)) * H_ + h * DH_;
  const float4 q4 = *(const float4*)(q + qoff + (lq << 2));
  const float* kb = k + (size_t)b * S_ * H_ + h * DH_;
  const float* vb = v + (size_t)b * S_ * H_ + h * DH_;
  float m = -INFINITY, l = 0.f;
  float4 o = make_float4(0.f, 0.f, 0.f, 0.f);
  for (int kk = 0; kk < S_; kk += 4) {
    const int key = kk + kg;
    const float4 k4 = *(const float4*)(kb + (size_t)key * H_ + (lq << 2));
    float s = q4.x * k4.x + q4.y * k4.y + q4.z * k4.z + q4.w * k4.w;
    s += __shfl_xor(s, 1); s += __shfl_xor(s, 2);
    s += __shfl_xor(s, 4); s += __shfl_xor(s, 8);       // per-16-lane-group dot
    s *= 0.125f;                                        // 1/sqrt(64)
    float mx = fmaxf(s, __shfl_xor(s, 16));
    mx = fmaxf(mx, __shfl_xor(mx, 32));                 // max over the 4 keys
    const float mn = fmaxf(m, mx);
    const float sc = __expf(m - mn);                    // m=-inf first iter -> 0
    const float e  = __expf(s - mn);
    float es = e + __shfl_xor(e, 16); es += __shfl_xor(es, 32);
    l = l * sc + es;
    const float4 v4 = *(const float4*)(vb + (size_t)key * H_ + (lq << 2));
    o.x = o.x * sc + e * v4.x; o.y = o.y * sc + e * v4.y;
    o.z = o.z * sc + e * v4.z; o.w = o.w * sc + e * v4.w;
    m = mn;
  }
  o.x += __shfl_xor(o.x, 16); o.x += __shfl_xor(o.x, 32);
  o.y += __shfl_xor(o.y, 16); o.y += __shfl_xor(o.y, 32);
  o.z += __shfl_xor(o.z, 16); o.z += __shfl_xor(o.z, 32);
  o.w += __shfl_xor(o.w, 16); o.w += __shfl_xor(o.w, 32);
  if (kg == 0) {
    const float inv = 1.f / l;
    float4 r = make_float4(o.x * inv, o.y * inv, o.z * inv, o.w * inv);
    *(float4*)(ctx + qoff + (lq << 2)) = r;
  }
}

// ---------- residual add + LayerNorm (row = 1024) ----------
__global__ __launch_bounds__(256) void add_ln_kernel(
    const float* __restrict__ a, const float* __restrict__ r,
    const float* __restrict__ g, const float* __restrict__ bta,
    float* __restrict__ out)
{
  const int row = blockIdx.x, tid = threadIdx.x;
  const size_t base = (size_t)row * H_;
  const float4 xa = *(const float4*)(a + base + (tid << 2));
  const float4 xr = *(const float4*)(r + base + (tid << 2));
  float4 x = make_float4(xa.x + xr.x, xa.y + xr.y, xa.z + xr.z, xa.w + xr.w);
  float s  = x.x + x.y + x.z + x.w;
  float ss = x.x * x.x + x.y * x.y + x.z * x.z + x.w * x.w;
#pragma unroll
  for (int off = 1; off < 64; off <<= 1) { s += __shfl_xor(s, off); ss += __shfl_xor(ss, off); }
  __shared__ float red[8];
  const int w = tid >> 6, ln = tid & 63;
  if (ln == 0) { red[w] = s; red[4 + w] = ss; }
  __syncthreads();
  const float S  = red[0] + red[1] + red[2] + red[3];
  const float SS = red[4] + red[5] + red[6] + red[7];
  const float mu  = S * (1.f / 1024.f);
  const float var = fmaxf(SS * (1.f / 1024.f) - mu * mu, 0.f);
  const float inv = rsqrtf(var + LN_EPS);
  const float4 gg = *(const float4*)(g + (tid << 2));
  const float4 bb = *(const float4*)(bta + (tid << 2));
  float4 y;
  y.x = (x.x - mu) * inv * gg.x + bb.x;
  y.y = (x.y - mu) * inv * gg.y + bb.y;
  y.z = (x.z - mu) * inv * gg.z + bb.z;
  y.w = (x.w - mu) * inv * gg.w + bb.w;
  *(float4*)(out + base + (tid << 2)) = y;
}

// ---------- router: logits + argmax (first max), count per expert ----------
__global__ __launch_bounds__(64) void router_kernel(
    const float* __restrict__ x, const float* __restrict__ rw,
    int* __restrict__ idx, int* __restrict__ cnt)
{
  const int t = blockIdx.x, lane = threadIdx.x;
  float acc[8] = {0.f};
  for (int c = 0; c < H_; c += 64) {
    const float xv = x[(size_t)t * H_ + c + lane];
    const float* wr = rw + (size_t)(c + lane) * E_;
    const float4 w0 = *(const float4*)wr;
    const float4 w1 = *(const float4*)(wr + 4);
    acc[0] += xv * w0.x; acc[1] += xv * w0.y; acc[2] += xv * w0.z; acc[3] += xv * w0.w;
    acc[4] += xv * w1.x; acc[5] += xv * w1.y; acc[6] += xv * w1.z; acc[7] += xv * w1.w;
  }
#pragma unroll
  for (int e = 0; e < E_; ++e) {
    float s = acc[e];
#pragma unroll
    for (int off = 1; off < 64; off <<= 1) s += __shfl_xor(s, off);
    acc[e] = s;
  }
  if (lane == 0) {
    int be_ = 0; float bv = acc[0];
#pragma unroll
    for (int e = 1; e < E_; ++e) if (acc[e] > bv) { bv = acc[e]; be_ = e; }  // strict > keeps first max
    idx[t] = be_;
    atomicAdd(&cnt[be_], 1);
  }
}

__global__ void init_kernel(int* cnt) { if (threadIdx.x < E_) cnt[threadIdx.x] = 0; }

__global__ void scan_kernel(const int* __restrict__ cnt, int* __restrict__ offs,
                            int* __restrict__ cursor, int* __restrict__ tb)
{
  int o = 0, tt = 0;
  for (int e = 0; e < E_; ++e) {
    offs[e] = o; cursor[e] = o; tb[e] = tt;
    o += cnt[e]; tt += (cnt[e] + 63) >> 6;
  }
  tb[E_] = tt;
}

__global__ __launch_bounds__(256) void scatter_kernel(
    const int* __restrict__ idx, int* __restrict__ cursor, int* __restrict__ lists)
{
  const int t = blockIdx.x * 256 + threadIdx.x;
  if (t < N_) {
    const int e = idx[t];
    const int p = atomicAdd(&cursor[e], 1);
    lists[p] = t;
  }
}

// ---------- MoE expert GEMM: gathered rows, gelu(x@We[e]+be[e]) -> bf16 ----------
__global__ __launch_bounds__(256) void moe_gemm_kernel(
    const float* __restrict__ X, const float* __restrict__ We,
    const float* __restrict__ be, const int* __restrict__ lists,
    const int* __restrict__ offs, const int* __restrict__ cnt,
    const int* __restrict__ tb, __hip_bfloat16* __restrict__ inter)
{
  __shared__ float As[16][64];
  __shared__ float Bs[16][68];
  __shared__ int tok[64];
  const int by = blockIdx.y;
  if (by >= tb[E_]) return;
  int e = 0;
#pragma unroll
  for (int t = 1; t < E_; ++t) if (by >= tb[t]) e = t;
  const int rt = by - tb[e];
  const int nv = cnt[e] - (rt << 6);
  const int tid = threadIdx.x;
  if (tid < 64) tok[tid] = (tid < nv) ? lists[offs[e] + (rt << 6) + tid] : -1;
  __syncthreads();
  const int tx = tid & 15, ty = tid >> 4;
  const int n0 = blockIdx.x << 6;
  const int lm = tid & 63, lk = (tid >> 6) << 2;
  const int bk = tid >> 4, bn = (tid & 15) << 2;
  const float* Wp = We + (size_t)e * H_ * I_;
  const int tA = tok[lm];
  float acc[4][4] = {{0.f}};
  for (int kt = 0; kt < H_; kt += 16) {
    float4 a4 = make_float4(0.f, 0.f, 0.f, 0.f);
    if (tA >= 0) a4 = *(const float4*)&X[(size_t)tA * H_ + kt + lk];
    const float4 b4 = *(const float4*)&Wp[(size_t)(kt + bk) * I_ + n0 + bn];
    __syncthreads();
    As[lk + 0][lm] = a4.x; As[lk + 1][lm] = a4.y;
    As[lk + 2][lm] = a4.z; As[lk + 3][lm] = a4.w;
    *(float4*)&Bs[bk][bn] = b4;
    __syncthreads();
#pragma unroll
    for (int k2 = 0; k2 < 16; ++k2) {
      const float a0 = As[k2][ty], a1 = As[k2][ty + 16],
                  a2 = As[k2][ty + 32], a3 = As[k2][ty + 48];
      const float4 b = *(const float4*)&Bs[k2][tx << 2];
      acc[0][0] += a0 * b.x; acc[0][1] += a0 * b.y; acc[0][2] += a0 * b.z; acc[0][3] += a0 * b.w;
      acc[1][0] += a1 * b.x; acc[1][1] += a1 * b.y; acc[1][2] += a1 * b.z; acc[1][3] += a1 * b.w;
      acc[2][0] += a2 * b.x; acc[2][1] += a2 * b.y; acc[2][2] += a2 * b.z; acc[2][3] += a2 * b.w;
      acc[3][0] += a3 * b.x; acc[3][1] += a3 * b.y; acc[3][2] += a3 * b.z; acc[3][3] += a3 * b.w;
    }
  }
  const float4 bias4 = *(const float4*)&be[(size_t)e * I_ + n0 + (tx << 2)];
#pragma unroll
  for (int i = 0; i < 4; ++i) {
    const int t = tok[ty + (i << 4)];
    if (t < 0) continue;
    float4 v;
    v.x = gelu_f(acc[i][0] + bias4.x); v.y = gelu_f(acc[i][1] + bias4.y);
    v.z = gelu_f(acc[i][2] + bias4.z); v.w = gelu_f(acc[i][3] + bias4.w);
    ushort4 u; u.x = f2bf(v.x); u.y = f2bf(v.y); u.z = f2bf(v.z); u.w = f2bf(v.w);
    *(ushort4*)&inter[(size_t)t * I_ + n0 + (tx << 2)] = u;
  }
}

// ---------- launch ----------
extern "C" void kernel_launch(void* const* d_in, const int* in_sizes, int n_in,
                              void* d_out, int out_size, void* d_ws, size_t ws_size,
                              hipStream_t stream) {
  const float* x   = (const float*)d_in[0];
  const float* Wq  = (const float*)d_in[1];
  const float* bq  = (const float*)d_in[2];
  const float* Wk  = (const float*)d_in[3];
  const float* bk  = (const float*)d_in[4];
  const float* Wv  = (const float*)d_in[5];
  const float* bv  = (const float*)d_in[6];
  const float* Wao = (const float*)d_in[7];
  const float* bao = (const float*)d_in[8];
  const float* g1  = (const float*)d_in[9];
  const float* b1  = (const float*)d_in[10];
  const float* rw  = (const float*)d_in[11];
  const float* We  = (const float*)d_in[12];
  const float* be  = (const float*)d_in[13];
  const float* Wo  = (const float*)d_in[14];
  const float* bo  = (const float*)d_in[15];
  const float* g2  = (const float*)d_in[16];
  const float* b2  = (const float*)d_in[17];
  float* out = (float*)d_out;

  char* p = (char*)d_ws;
  int* idx    = (int*)p; p += (size_t)N_ * 4;
  int* cnt    = (int*)p; p += 8 * 4;
  int* offs   = (int*)p; p += 8 * 4;
  int* cursor = (int*)p; p += 8 * 4;
  int* tb     = (int*)p; p += 16 * 4;
  int* lists  = (int*)p; p += (size_t)N_ * 4;
  p = (char*)(((uintptr_t)p + 255) & ~(uintptr_t)255);
  const size_t NHf = (size_t)N_ * H_;
  float* qb   = (float*)p; p += NHf * 4;
  float* kb2  = (float*)p; p += NHf * 4;
  float* vb2  = (float*)p; p += NHf * 4;
  float* ctxb = (float*)p; p += NHf * 4;
  float* attn = (float*)p; p += NHf * 4;
  __hip_bfloat16* interb = (__hip_bfloat16*)p;  // N_*I_ bf16 (33.5 MB)

  const dim3 blk(256);
  const dim3 gHH(H_ / 64, N_ / 64);

  init_kernel<<<1, 64, 0, stream>>>(cnt);
  gemm_bias_kernel<float><<<gHH, blk, 0, stream>>>(x, Wq, bq, qb,  N_, H_, H_);
  gemm_bias_kernel<float><<<gHH, blk, 0, stream>>>(x, Wk, bk, kb2, N_, H_, H_);
  gemm_bias_kernel<float><<<gHH, blk, 0, stream>>>(x, Wv, bv, vb2, N_, H_, H_);
  attn_kernel<<<(B_ * NH_ * S_) / 4, blk, 0, stream>>>(qb, kb2, vb2, ctxb);
  gemm_bias_kernel<float><<<gHH, blk, 0, stream>>>(ctxb, Wao, bao, qb, N_, H_, H_);  // qb = t1
  add_ln_kernel<<<N_, blk, 0, stream>>>(qb, x, g1, b1, attn);
  router_kernel<<<N_, 64, 0, stream>>>(attn, rw, idx, cnt);
  scan_kernel<<<1, 1, 0, stream>>>(cnt, offs, cursor, tb);
  scatter_kernel<<<N_ / 256, blk, 0, stream>>>(idx, cursor, lists);
  moe_gemm_kernel<<<dim3(I_ / 64, N_ / 64 + E_), blk, 0, stream>>>(
      attn, We, be, lists, offs, cnt, tb, interb);
  gemm_bias_kernel<__hip_bfloat16><<<gHH, blk, 0, stream>>>(interb, Wo, bo, kb2, N_, I_, H_);
  add_ln_kernel<<<N_, blk, 0, stream>>>(kb2, attn, g2, b2, out);
}

// Round 4
// 1941.334 us; speedup vs baseline: 2.4171x; 2.4171x over previous
//
#include <hip/hip_runtime.h>
#include <hip/hip_bf16.h>
#include <cstdint>

#define H_  1024
#define NH_ 16
#define DH_ 64
#define I_  4096
#define E_  8
#define B_  2
#define S_  2048
#define N_  4096        // B_*S_
#define LN_EPS 1e-12f

typedef __attribute__((ext_vector_type(4))) float f4;
typedef __attribute__((ext_vector_type(8))) short s8v;
typedef __attribute__((ext_vector_type(4))) short s4v;
typedef unsigned int u32;

// ---------- helpers ----------
__device__ __forceinline__ float bf2f(unsigned short u) {
  union { unsigned int i; float f; } c; c.i = ((unsigned int)u) << 16; return c.f;
}
__device__ __forceinline__ unsigned short f2bf(float f) {
  __hip_bfloat16 h = __float2bfloat16(f);
  return *reinterpret_cast<unsigned short*>(&h);
}
__device__ __forceinline__ u32 pack_bf2(float a, float b) {
  return (u32)f2bf(a) | ((u32)f2bf(b) << 16);
}
__device__ __forceinline__ float4 load4f(const float* p) { return *(const float4*)p; }
__device__ __forceinline__ float4 load4f(const __hip_bfloat16* p) {
  const ushort4 u = *(const ushort4*)p;
  float4 r; r.x = bf2f(u.x); r.y = bf2f(u.y); r.z = bf2f(u.z); r.w = bf2f(u.w); return r;
}
__device__ __forceinline__ float gelu_f(float x) {
  return 0.5f * x * (1.0f + erff(x * 0.70710678118f));   // exact GELU
}

// ---------- generic fp32 GEMM: C = A*W + bias ----------
template <typename TA>
__global__ __launch_bounds__(256) void gemm_bias_kernel(
    const TA* __restrict__ A, const float* __restrict__ W,
    const float* __restrict__ bias, float* __restrict__ C,
    int M, int K, int Nn)
{
  __shared__ float As[16][64];   // [k][m]
  __shared__ float Bs[16][68];   // [k][n] padded
  const int tid = threadIdx.x;
  const int tx = tid & 15, ty = tid >> 4;
  const int m0 = blockIdx.y << 6, n0 = blockIdx.x << 6;
  const int lm = tid & 63, lk = (tid >> 6) << 2;
  const int bk = tid >> 4, bn = (tid & 15) << 2;
  float acc[4][4] = {{0.f}};
  for (int kt = 0; kt < K; kt += 16) {
    const float4 a4 = load4f(&A[(size_t)(m0 + lm) * K + kt + lk]);
    const float4 b4 = *(const float4*)&W[(size_t)(kt + bk) * Nn + n0 + bn];
    __syncthreads();
    As[lk + 0][lm] = a4.x; As[lk + 1][lm] = a4.y;
    As[lk + 2][lm] = a4.z; As[lk + 3][lm] = a4.w;
    *(float4*)&Bs[bk][bn] = b4;
    __syncthreads();
#pragma unroll
    for (int k2 = 0; k2 < 16; ++k2) {
      const float a0 = As[k2][ty], a1 = As[k2][ty + 16],
                  a2 = As[k2][ty + 32], a3 = As[k2][ty + 48];
      const float4 b = *(const float4*)&Bs[k2][tx << 2];
      acc[0][0] += a0 * b.x; acc[0][1] += a0 * b.y; acc[0][2] += a0 * b.z; acc[0][3] += a0 * b.w;
      acc[1][0] += a1 * b.x; acc[1][1] += a1 * b.y; acc[1][2] += a1 * b.z; acc[1][3] += a1 * b.w;
      acc[2][0] += a2 * b.x; acc[2][1] += a2 * b.y; acc[2][2] += a2 * b.z; acc[2][3] += a2 * b.w;
      acc[3][0] += a3 * b.x; acc[3][1] += a3 * b.y; acc[3][2] += a3 * b.z; acc[3][3] += a3 * b.w;
    }
  }
  const float4 bias4 = *(const float4*)&bias[n0 + (tx << 2)];
#pragma unroll
  for (int i = 0; i < 4; ++i) {
    const int row = m0 + ty + (i << 4);
    float4 v;
    v.x = acc[i][0] + bias4.x; v.y = acc[i][1] + bias4.y;
    v.z = acc[i][2] + bias4.z; v.w = acc[i][3] + bias4.w;
    *(float4*)&C[(size_t)row * Nn + n0 + (tx << 2)] = v;
  }
}

// ---------- MFMA flash attention (all-builtin, P via LDS) ----------
// Grid: 1024 blocks (32 bh * 32 qtiles), 256 threads (4 waves), 16 q/wave.
// Swapped QK^T (A=K_tile, B=Q): C-layout (verified: row=(l>>4)*4+r, col=l&15)
// => lane l holds S[key=st*16+g*4+r][query=lq]. P round-trips through LDS so
// PV can use the same 16x16x32 builtin with per-lane-consistent k ordering.
__global__ __launch_bounds__(256) void attn_mfma_kernel(
    const float* __restrict__ q, const float* __restrict__ k,
    const float* __restrict__ v, float* __restrict__ ctx)
{
  __shared__ __align__(16) short Ks[64 * 72];      // [key][d]   stride 72
  __shared__ __align__(16) short Vt[64 * 72];      // [d][key]   stride 72
  __shared__ __align__(16) short Ps[4][16 * 72];   // per-wave P [query][key]
  const int bid0 = blockIdx.x;
  const int bid  = ((bid0 & 7) << 7) + (bid0 >> 3);   // bijective XCD swizzle
  const int bh = bid >> 5, qt = bid & 31;
  const int b = bh >> 4, h = bh & 15;
  const int tid = threadIdx.x, w = tid >> 6, l = tid & 63;
  const int lq = l & 15, g = l >> 4;
  const size_t bS = (size_t)b * S_;
  const float* qb = q + bS * H_ + h * DH_;
  const float* kb = k + bS * H_ + h * DH_;
  const float* vb = v + bS * H_ + h * DH_;

  // Q fragments: lane l holds Q[qt*64 + w*16 + lq][dsub*32 + g*8 + j]
  s8v qf0, qf1;
  {
    const float* qp = qb + (size_t)(qt * 64 + w * 16 + lq) * H_ + g * 8;
    const f4 x0 = *(const f4*)(qp);      const f4 x1 = *(const f4*)(qp + 4);
    const f4 y0 = *(const f4*)(qp + 32); const f4 y1 = *(const f4*)(qp + 36);
#pragma unroll
    for (int j = 0; j < 4; ++j) {
      qf0[j] = (short)f2bf(x0[j]); qf0[j + 4] = (short)f2bf(x1[j]);
      qf1[j] = (short)f2bf(y0[j]); qf1[j + 4] = (short)f2bf(y1[j]);
    }
  }

  f4 o0 = {0,0,0,0}, o1 = {0,0,0,0}, o2 = {0,0,0,0}, o3 = {0,0,0,0};
  float mrun = -3.0e38f, lrun = 0.f;

  const int skey = tid >> 2;           // staging: key row 0..63
  const int sd   = (tid & 3) << 4;     // staging: d start {0,16,32,48}

  for (int kt = 0; kt < 32; ++kt) {
    __syncthreads();
    // ---- stage K tile [key][d] and V tile transposed [d][key] ----
    {
      const float* kp = kb + (size_t)(kt * 64 + skey) * H_ + sd;
#pragma unroll
      for (int i = 0; i < 4; ++i) {
        const f4 kv = *(const f4*)(kp + 4 * i);
        s4v t;
        t[0] = (short)f2bf(kv[0]); t[1] = (short)f2bf(kv[1]);
        t[2] = (short)f2bf(kv[2]); t[3] = (short)f2bf(kv[3]);
        *(s4v*)&Ks[skey * 72 + sd + 4 * i] = t;
      }
      const float* vp = vb + (size_t)(kt * 64 + skey) * H_ + sd;
#pragma unroll
      for (int i = 0; i < 4; ++i) {
        const f4 vv = *(const f4*)(vp + 4 * i);
#pragma unroll
        for (int ii = 0; ii < 4; ++ii)
          Vt[(sd + 4 * i + ii) * 72 + skey] = (short)f2bf(vv[ii]);
      }
    }
    __syncthreads();

    // ---- QK^T: lane l holds S[key=st*16+4g+r][query=lq] ----
    float s[16];
#pragma unroll
    for (int st = 0; st < 4; ++st) {
      f4 acc = {0, 0, 0, 0};
      const s8v ka0 = *(const s8v*)&Ks[(st * 16 + lq) * 72 + (g << 3)];
      const s8v ka1 = *(const s8v*)&Ks[(st * 16 + lq) * 72 + 32 + (g << 3)];
      acc = __builtin_amdgcn_mfma_f32_16x16x32_bf16(ka0, qf0, acc, 0, 0, 0);
      acc = __builtin_amdgcn_mfma_f32_16x16x32_bf16(ka1, qf1, acc, 0, 0, 0);
      s[st * 4 + 0] = acc[0] * 0.125f; s[st * 4 + 1] = acc[1] * 0.125f;
      s[st * 4 + 2] = acc[2] * 0.125f; s[st * 4 + 3] = acc[3] * 0.125f;
    }

    // ---- online softmax over the 64-key tile (per query lq) ----
    float tmax = s[0];
#pragma unroll
    for (int i = 1; i < 16; ++i) tmax = fmaxf(tmax, s[i]);
    tmax = fmaxf(tmax, __shfl_xor(tmax, 16));
    tmax = fmaxf(tmax, __shfl_xor(tmax, 32));
    const float mnew  = fmaxf(mrun, tmax);
    const float alpha = __expf(mrun - mnew);
    float psum = 0.f;
#pragma unroll
    for (int i = 0; i < 16; ++i) { s[i] = __expf(s[i] - mnew); psum += s[i]; }
    psum += __shfl_xor(psum, 16); psum += __shfl_xor(psum, 32);
    lrun = lrun * alpha + psum; mrun = mnew;

    // O rescale: O rows are q=4g+r; alpha for query q lives at lane q
    f4 av;
    av[0] = __shfl(alpha, g * 4 + 0); av[1] = __shfl(alpha, g * 4 + 1);
    av[2] = __shfl(alpha, g * 4 + 2); av[3] = __shfl(alpha, g * 4 + 3);
    o0 *= av; o1 *= av; o2 *= av; o3 *= av;

    // ---- write P to per-wave LDS: Ps[w][query][key] ----
    {
      short* pw = &Ps[w][lq * 72];
#pragma unroll
      for (int st = 0; st < 4; ++st) {
        *(u32*)&pw[st * 16 + g * 4 + 0] = pack_bf2(s[st * 4 + 0], s[st * 4 + 1]);
        *(u32*)&pw[st * 16 + g * 4 + 2] = pack_bf2(s[st * 4 + 2], s[st * 4 + 3]);
      }
    }
    // same-wave DS ordering; drain LDS queue before cross-lane read
    asm volatile("s_waitcnt lgkmcnt(0)" ::: "memory");
    __builtin_amdgcn_sched_barrier(0);

    // ---- PV: O += P * V, 16x16x32 builtin, K=64 as 2 steps ----
#pragma unroll
    for (int ks = 0; ks < 2; ++ks) {
      const int kof = ks * 32 + (g << 3);
      const s8v pa = *(const s8v*)&Ps[w][lq * 72 + kof];
      const s8v v0 = *(const s8v*)&Vt[( 0 + lq) * 72 + kof];
      const s8v v1 = *(const s8v*)&Vt[(16 + lq) * 72 + kof];
      const s8v v2 = *(const s8v*)&Vt[(32 + lq) * 72 + kof];
      const s8v v3 = *(const s8v*)&Vt[(48 + lq) * 72 + kof];
      o0 = __builtin_amdgcn_mfma_f32_16x16x32_bf16(pa, v0, o0, 0, 0, 0);
      o1 = __builtin_amdgcn_mfma_f32_16x16x32_bf16(pa, v1, o1, 0, 0, 0);
      o2 = __builtin_amdgcn_mfma_f32_16x16x32_bf16(pa, v2, o2, 0, 0, 0);
      o3 = __builtin_amdgcn_mfma_f32_16x16x32_bf16(pa, v3, o3, 0, 0, 0);
    }
  }

  // ---- epilogue: normalize + store (row q = 4g+r, col d = lq + 16*blk) ----
  const float inv = 1.f / lrun;
#pragma unroll
  for (int r = 0; r < 4; ++r) {
    const float li = __shfl(inv, g * 4 + r);
    float* op = ctx + (bS + (size_t)(qt * 64 + w * 16 + g * 4 + r)) * H_ + h * DH_ + lq;
    op[0]  = o0[r] * li;
    op[16] = o1[r] * li;
    op[32] = o2[r] * li;
    op[48] = o3[r] * li;
  }
}

// ---------- residual add + LayerNorm (row = 1024) ----------
__global__ __launch_bounds__(256) void add_ln_kernel(
    const float* __restrict__ a, const float* __restrict__ r,
    const float* __restrict__ g, const float* __restrict__ bta,
    float* __restrict__ out)
{
  const int row = blockIdx.x, tid = threadIdx.x;
  const size_t base = (size_t)row * H_;
  const float4 xa = *(const float4*)(a + base + (tid << 2));
  const float4 xr = *(const float4*)(r + base + (tid << 2));
  float4 x = make_float4(xa.x + xr.x, xa.y + xr.y, xa.z + xr.z, xa.w + xr.w);
  float s  = x.x + x.y + x.z + x.w;
  float ss = x.x * x.x + x.y * x.y + x.z * x.z + x.w * x.w;
#pragma unroll
  for (int off = 1; off < 64; off <<= 1) { s += __shfl_xor(s, off); ss += __shfl_xor(ss, off); }
  __shared__ float red[8];
  const int w = tid >> 6, ln = tid & 63;
  if (ln == 0) { red[w] = s; red[4 + w] = ss; }
  __syncthreads();
  const float S  = red[0] + red[1] + red[2] + red[3];
  const float SS = red[4] + red[5] + red[6] + red[7];
  const float mu  = S * (1.f / 1024.f);
  const float var = fmaxf(SS * (1.f / 1024.f) - mu * mu, 0.f);
  const float inv = rsqrtf(var + LN_EPS);
  const float4 gg = *(const float4*)&g[tid << 2];
  const float4 bb = *(const float4*)&bta[tid << 2];
  float4 y;
  y.x = (x.x - mu) * inv * gg.x + bb.x;
  y.y = (x.y - mu) * inv * gg.y + bb.y;
  y.z = (x.z - mu) * inv * gg.z + bb.z;
  y.w = (x.w - mu) * inv * gg.w + bb.w;
  *(float4*)&out[base + (tid << 2)] = y;
}

// ---------- router ----------
__global__ __launch_bounds__(64) void router_kernel(
    const float* __restrict__ x, const float* __restrict__ rw,
    int* __restrict__ idx, int* __restrict__ cnt)
{
  const int t = blockIdx.x, lane = threadIdx.x;
  float acc[8] = {0.f};
  for (int c = 0; c < H_; c += 64) {
    const float xv = x[(size_t)t * H_ + c + lane];
    const float* wr = rw + (size_t)(c + lane) * E_;
    const float4 w0 = *(const float4*)wr;
    const float4 w1 = *(const float4*)(wr + 4);
    acc[0] += xv * w0.x; acc[1] += xv * w0.y; acc[2] += xv * w0.z; acc[3] += xv * w0.w;
    acc[4] += xv * w1.x; acc[5] += xv * w1.y; acc[6] += xv * w1.z; acc[7] += xv * w1.w;
  }
#pragma unroll
  for (int e = 0; e < E_; ++e) {
    float s = acc[e];
#pragma unroll
    for (int off = 1; off < 64; off <<= 1) s += __shfl_xor(s, off);
    acc[e] = s;
  }
  if (lane == 0) {
    int be_ = 0; float bv = acc[0];
#pragma unroll
    for (int e = 1; e < E_; ++e) if (acc[e] > bv) { bv = acc[e]; be_ = e; }
    idx[t] = be_;
    atomicAdd(&cnt[be_], 1);
  }
}

__global__ void init_kernel(int* cnt) { if (threadIdx.x < E_) cnt[threadIdx.x] = 0; }

__global__ void scan_kernel(const int* __restrict__ cnt, int* __restrict__ offs,
                            int* __restrict__ cursor, int* __restrict__ tb)
{
  int o = 0, tt = 0;
  for (int e = 0; e < E_; ++e) {
    offs[e] = o; cursor[e] = o; tb[e] = tt;
    o += cnt[e]; tt += (cnt[e] + 63) >> 6;
  }
  tb[E_] = tt;
}

__global__ __launch_bounds__(256) void scatter_kernel(
    const int* __restrict__ idx, int* __restrict__ cursor, int* __restrict__ lists)
{
  const int t = blockIdx.x * 256 + threadIdx.x;
  if (t < N_) {
    const int e = idx[t];
    const int p = atomicAdd(&cursor[e], 1);
    lists[p] = t;
  }
}

// ---------- MoE expert GEMM ----------
__global__ __launch_bounds__(256) void moe_gemm_kernel(
    const float* __restrict__ X, const float* __restrict__ We,
    const float* __restrict__ be, const int* __restrict__ lists,
    const int* __restrict__ offs, const int* __restrict__ cnt,
    const int* __restrict__ tb, __hip_bfloat16* __restrict__ inter)
{
  __shared__ float As[16][64];
  __shared__ float Bs[16][68];
  __shared__ int tok[64];
  const int by = blockIdx.y;
  if (by >= tb[E_]) return;
  int e = 0;
#pragma unroll
  for (int t = 1; t < E_; ++t) if (by >= tb[t]) e = t;
  const int rt = by - tb[e];
  const int nv = cnt[e] - (rt << 6);
  const int tid = threadIdx.x;
  if (tid < 64) tok[tid] = (tid < nv) ? lists[offs[e] + (rt << 6) + tid] : -1;
  __syncthreads();
  const int tx = tid & 15, ty = tid >> 4;
  const int n0 = blockIdx.x << 6;
  const int lm = tid & 63, lk = (tid >> 6) << 2;
  const int bk = tid >> 4, bn = (tid & 15) << 2;
  const float* Wp = We + (size_t)e * H_ * I_;
  const int tA = tok[lm];
  float acc[4][4] = {{0.f}};
  for (int kt = 0; kt < H_; kt += 16) {
    float4 a4 = make_float4(0.f, 0.f, 0.f, 0.f);
    if (tA >= 0) a4 = *(const float4*)&X[(size_t)tA * H_ + kt + lk];
    const float4 b4 = *(const float4*)&Wp[(size_t)(kt + bk) * I_ + n0 + bn];
    __syncthreads();
    As[lk + 0][lm] = a4.x; As[lk + 1][lm] = a4.y;
    As[lk + 2][lm] = a4.z; As[lk + 3][lm] = a4.w;
    *(float4*)&Bs[bk][bn] = b4;
    __syncthreads();
#pragma unroll
    for (int k2 = 0; k2 < 16; ++k2) {
      const float a0 = As[k2][ty], a1 = As[k2][ty + 16],
                  a2 = As[k2][ty + 32], a3 = As[k2][ty + 48];
      const float4 b = *(const float4*)&Bs[k2][tx << 2];
      acc[0][0] += a0 * b.x; acc[0][1] += a0 * b.y; acc[0][2] += a0 * b.z; acc[0][3] += a0 * b.w;
      acc[1][0] += a1 * b.x; acc[1][1] += a1 * b.y; acc[1][2] += a1 * b.z; acc[1][3] += a1 * b.w;
      acc[2][0] += a2 * b.x; acc[2][1] += a2 * b.y; acc[2][2] += a2 * b.z; acc[2][3] += a2 * b.w;
      acc[3][0] += a3 * b.x; acc[3][1] += a3 * b.y; acc[3][2] += a3 * b.z; acc[3][3] += a3 * b.w;
    }
  }
  const float4 bias4 = *(const float4*)&be[(size_t)e * I_ + n0 + (tx << 2)];
#pragma unroll
  for (int i = 0; i < 4; ++i) {
    const int t = tok[ty + (i << 4)];
    if (t < 0) continue;
    float4 v;
    v.x = gelu_f(acc[i][0] + bias4.x); v.y = gelu_f(acc[i][1] + bias4.y);
    v.z = gelu_f(acc[i][2] + bias4.z); v.w = gelu_f(acc[i][3] + bias4.w);
    ushort4 u; u.x = f2bf(v.x); u.y = f2bf(v.y); u.z = f2bf(v.z); u.w = f2bf(v.w);
    *(ushort4*)&inter[(size_t)t * I_ + n0 + (tx << 2)] = u;
  }
}

// ---------- launch ----------
extern "C" void kernel_launch(void* const* d_in, const int* in_sizes, int n_in,
                              void* d_out, int out_size, void* d_ws, size_t ws_size,
                              hipStream_t stream) {
  const float* x   = (const float*)d_in[0];
  const float* Wq  = (const float*)d_in[1];
  const float* bq  = (const float*)d_in[2];
  const float* Wk  = (const float*)d_in[3];
  const float* bk  = (const float*)d_in[4];
  const float* Wv  = (const float*)d_in[5];
  const float* bv  = (const float*)d_in[6];
  const float* Wao = (const float*)d_in[7];
  const float* bao = (const float*)d_in[8];
  const float* g1  = (const float*)d_in[9];
  const float* b1  = (const float*)d_in[10];
  const float* rw  = (const float*)d_in[11];
  const float* We  = (const float*)d_in[12];
  const float* be  = (const float*)d_in[13];
  const float* Wo  = (const float*)d_in[14];
  const float* bo  = (const float*)d_in[15];
  const float* g2  = (const float*)d_in[16];
  const float* b2  = (const float*)d_in[17];
  float* out = (float*)d_out;

  char* p = (char*)d_ws;
  int* idx    = (int*)p; p += (size_t)N_ * 4;
  int* cnt    = (int*)p; p += 8 * 4;
  int* offs   = (int*)p; p += 8 * 4;
  int* cursor = (int*)p; p += 8 * 4;
  int* tb     = (int*)p; p += 16 * 4;
  int* lists  = (int*)p; p += (size_t)N_ * 4;
  p = (char*)(((uintptr_t)p + 255) & ~(uintptr_t)255);
  const size_t NHf = (size_t)N_ * H_;
  float* qb   = (float*)p; p += NHf * 4;
  float* kb2  = (float*)p; p += NHf * 4;
  float* vb2  = (float*)p; p += NHf * 4;
  float* ctxb = (float*)p; p += NHf * 4;
  float* attn = (float*)p; p += NHf * 4;
  __hip_bfloat16* interb = (__hip_bfloat16*)p;  // N_*I_ bf16

  const dim3 blk(256);
  const dim3 gHH(H_ / 64, N_ / 64);

  init_kernel<<<1, 64, 0, stream>>>(cnt);
  gemm_bias_kernel<float><<<gHH, blk, 0, stream>>>(x, Wq, bq, qb,  N_, H_, H_);
  gemm_bias_kernel<float><<<gHH, blk, 0, stream>>>(x, Wk, bk, kb2, N_, H_, H_);
  gemm_bias_kernel<float><<<gHH, blk, 0, stream>>>(x, Wv, bv, vb2, N_, H_, H_);
  attn_mfma_kernel<<<1024, blk, 0, stream>>>(qb, kb2, vb2, ctxb);
  gemm_bias_kernel<float><<<gHH, blk, 0, stream>>>(ctxb, Wao, bao, qb, N_, H_, H_);
  add_ln_kernel<<<N_, blk, 0, stream>>>(qb, x, g1, b1, attn);
  router_kernel<<<N_, 64, 0, stream>>>(attn, rw, idx, cnt);
  scan_kernel<<<1, 1, 0, stream>>>(cnt, offs, cursor, tb);
  scatter_kernel<<<N_ / 256, blk, 0, stream>>>(idx, cursor, lists);
  moe_gemm_kernel<<<dim3(I_ / 64, N_ / 64 + E_), blk, 0, stream>>>(
      attn, We, be, lists, offs, cnt, tb, interb);
  gemm_bias_kernel<__hip_bfloat16><<<gHH, blk, 0, stream>>>(interb, Wo, bo, kb2, N_, I_, H_);
  add_ln_kernel<<<N_, blk, 0, stream>>>(kb2, attn, g2, b2, out);
}

// Round 5
// 616.579 us; speedup vs baseline: 7.6102x; 3.1486x over previous
//
#include <hip/hip_runtime.h>
#include <hip/hip_bf16.h>
#include <cstdint>

#define H_  1024
#define NH_ 16
#define DH_ 64
#define I_  4096
#define E_  8
#define B_  2
#define S_  2048
#define N_  4096        // B_*S_
#define QKVLD 3072      // fused qkv row stride
#define LN_EPS 1e-12f

typedef __attribute__((ext_vector_type(4))) float f4;
typedef __attribute__((ext_vector_type(8))) short s8v;
typedef unsigned int u32;

// ---------- helpers ----------
__device__ __forceinline__ float bf2f(unsigned short u) {
  union { unsigned int i; float f; } c; c.i = ((unsigned int)u) << 16; return c.f;
}
__device__ __forceinline__ unsigned short f2bf(float f) {
  __hip_bfloat16 h = __float2bfloat16(f);
  return *reinterpret_cast<unsigned short*>(&h);
}
__device__ __forceinline__ u32 pack_bf2(float a, float b) {
  return (u32)f2bf(a) | ((u32)f2bf(b) << 16);
}
__device__ __forceinline__ float gelu_f(float x) {
  return 0.5f * x * (1.0f + erff(x * 0.70710678118f));   // exact GELU
}
__device__ __forceinline__ void gload16(const void* g, void* l) {
  __builtin_amdgcn_global_load_lds(
      (const __attribute__((address_space(1))) void*)g,
      (__attribute__((address_space(3))) void*)l, 16, 0, 0);
}

// ---------- fp32 -> bf16 elementwise ----------
__global__ __launch_bounds__(256) void cvt_bf16_kernel(
    const float* __restrict__ in, ushort* __restrict__ out, int n8)
{
  const int t = blockIdx.x * 256 + threadIdx.x;
  if (t >= n8) return;
  const f4 x0 = *(const f4*)(in + (size_t)t * 8);
  const f4 x1 = *(const f4*)(in + (size_t)t * 8 + 4);
  s8v o;
#pragma unroll
  for (int j = 0; j < 4; ++j) { o[j] = (short)f2bf(x0[j]); o[4 + j] = (short)f2bf(x1[j]); }
  *(s8v*)(out + (size_t)t * 8) = o;
}

// ---------- fp32 [R][C] -> bf16 [C][R] transpose ----------
__global__ __launch_bounds__(256) void transpose_cvt_kernel(
    const float* __restrict__ in, ushort* __restrict__ out, int R, int C)
{
  __shared__ float tile[32][33];
  const size_t zo = (size_t)blockIdx.z * R * C;
  const int bx = blockIdx.x << 5, by = blockIdx.y << 5;
  const int tx = threadIdx.x & 31, ty = threadIdx.x >> 5;   // ty 0..7
  const float* ip = in + zo + (size_t)by * C + bx;
#pragma unroll
  for (int i = 0; i < 4; ++i)
    tile[ty + 8 * i][tx] = ip[(size_t)(ty + 8 * i) * C + tx];
  __syncthreads();
  ushort* op = out + zo + (size_t)bx * R + by;
#pragma unroll
  for (int i = 0; i < 4; ++i)
    op[(size_t)(ty + 8 * i) * R + tx] = f2bf(tile[tx][ty + 8 * i]);
}

__global__ void concat3_kernel(const float* a, const float* b, const float* c,
                               float* __restrict__ o)
{
  const int t = blockIdx.x * 256 + threadIdx.x;   // 3072 total
  if (t < 1024) o[t] = a[t];
  else if (t < 2048) o[t] = b[t - 1024];
  else o[t] = c[t - 2048];
}

// ---------- MFMA GEMM: C = A * W + bias ----------
// A [M,K] bf16 row-major, Bt = W^T [N,K] bf16 row-major. 128x128 tile, BK=32.
// LDS layout [kslot(4)][row(128)][8 bf16]: frag reads are 2-way-bank (free).
// 4 waves as 2x2 quadrants of 64x64; 16 accumulators of 16x16x32 each.
template <bool BF16OUT>
__global__ __launch_bounds__(256) void gemm_mfma_kernel(
    const ushort* __restrict__ A, const ushort* __restrict__ Bt,
    const float* __restrict__ bias, void* __restrict__ Cout,
    const int M, const int N, const int K)
{
  __shared__ __align__(16) ushort Asm[4][128][8];
  __shared__ __align__(16) ushort Bsm[4][128][8];
  const int tid = threadIdx.x;
  const int w = tid >> 6, l = tid & 63;
  const int lq = l & 15, g = l >> 4;
  const int wm = w >> 1, wn = w & 1;
  const int m0 = blockIdx.y << 7, n0 = blockIdx.x << 7;

  // wave w stages kslot w; rows l and 64+l (LDS writes are base + lane*16B)
  const ushort* a0 = A + (size_t)(m0 + l) * K + (w << 3);
  const ushort* a1 = A + (size_t)(m0 + 64 + l) * K + (w << 3);
  const ushort* b0 = Bt + (size_t)(n0 + l) * K + (w << 3);
  const ushort* b1 = Bt + (size_t)(n0 + 64 + l) * K + (w << 3);
  ushort* ldsA0 = &Asm[w][0][0];  ushort* ldsA1 = &Asm[w][64][0];
  ushort* ldsB0 = &Bsm[w][0][0];  ushort* ldsB1 = &Bsm[w][64][0];

  f4 acc[4][4] = {};
  for (int kt = 0; kt < K; kt += 32) {
    __syncthreads();
    gload16(a0 + kt, ldsA0);
    gload16(a1 + kt, ldsA1);
    gload16(b0 + kt, ldsB0);
    gload16(b1 + kt, ldsB1);
    __syncthreads();   // waitcnt vmcnt(0) implied before barrier
    s8v af[4], bfv[4];
#pragma unroll
    for (int mi = 0; mi < 4; ++mi)
      af[mi] = *(const s8v*)&Asm[g][(wm << 6) + (mi << 4) + lq][0];
#pragma unroll
    for (int ni = 0; ni < 4; ++ni)
      bfv[ni] = *(const s8v*)&Bsm[g][(wn << 6) + (ni << 4) + lq][0];
#pragma unroll
    for (int mi = 0; mi < 4; ++mi)
#pragma unroll
      for (int ni = 0; ni < 4; ++ni)
        acc[mi][ni] = __builtin_amdgcn_mfma_f32_16x16x32_bf16(af[mi], bfv[ni], acc[mi][ni], 0, 0, 0);
  }
#pragma unroll
  for (int ni = 0; ni < 4; ++ni) {
    const int col = n0 + (wn << 6) + (ni << 4) + lq;
    const float bs = bias[col];
#pragma unroll
    for (int mi = 0; mi < 4; ++mi) {
      const int row = m0 + (wm << 6) + (mi << 4) + (g << 2);
#pragma unroll
      for (int r = 0; r < 4; ++r) {
        const float val = acc[mi][ni][r] + bs;
        if constexpr (BF16OUT) ((ushort*)Cout)[(size_t)(row + r) * N + col] = f2bf(val);
        else                   ((float*)Cout)[(size_t)(row + r) * N + col] = val;
      }
    }
  }
}

// ---------- MoE expert GEMM (MFMA): inter = gelu(gather(X) * We[e] + be[e]) ----------
__global__ __launch_bounds__(256) void moe_mfma_kernel(
    const ushort* __restrict__ X, const ushort* __restrict__ WeT,
    const float* __restrict__ be, const int* __restrict__ lists,
    const int* __restrict__ offs, const int* __restrict__ cnt,
    const int* __restrict__ tb, ushort* __restrict__ inter)
{
  __shared__ __align__(16) ushort Asm[4][128][8];
  __shared__ __align__(16) ushort Bsm[4][128][8];
  __shared__ int tokL[128];
  const int by = blockIdx.y;
  if (by >= tb[E_]) return;
  int e = 0;
#pragma unroll
  for (int t = 1; t < E_; ++t) if (by >= tb[t]) e = t;
  const int rt = by - tb[e];
  const int base = offs[e] + (rt << 7);
  const int nrows = cnt[e] - (rt << 7);
  const int tid = threadIdx.x;
  if (tid < 128) tokL[tid] = (tid < nrows) ? lists[base + tid] : -1;
  const int w = tid >> 6, l = tid & 63;
  const int lq = l & 15, g = l >> 4;
  const int wm = w >> 1, wn = w & 1;
  const int n0 = blockIdx.x << 7;
  // gather tokens for this thread's two A staging rows (clamped; rows >= nrows
  // produce garbage that is never written out)
  const int t0 = (l < nrows) ? lists[base + l] : lists[base];
  const int t1 = (64 + l < nrows) ? lists[base + 64 + l] : lists[base];
  const ushort* a0 = X + (size_t)t0 * H_ + (w << 3);
  const ushort* a1 = X + (size_t)t1 * H_ + (w << 3);
  const ushort* Wp = WeT + (size_t)e * I_ * H_;
  const ushort* b0 = Wp + (size_t)(n0 + l) * H_ + (w << 3);
  const ushort* b1 = Wp + (size_t)(n0 + 64 + l) * H_ + (w << 3);
  ushort* ldsA0 = &Asm[w][0][0];  ushort* ldsA1 = &Asm[w][64][0];
  ushort* ldsB0 = &Bsm[w][0][0];  ushort* ldsB1 = &Bsm[w][64][0];

  f4 acc[4][4] = {};
  for (int kt = 0; kt < H_; kt += 32) {
    __syncthreads();
    gload16(a0 + kt, ldsA0);
    gload16(a1 + kt, ldsA1);
    gload16(b0 + kt, ldsB0);
    gload16(b1 + kt, ldsB1);
    __syncthreads();
    s8v af[4], bfv[4];
#pragma unroll
    for (int mi = 0; mi < 4; ++mi)
      af[mi] = *(const s8v*)&Asm[g][(wm << 6) + (mi << 4) + lq][0];
#pragma unroll
    for (int ni = 0; ni < 4; ++ni)
      bfv[ni] = *(const s8v*)&Bsm[g][(wn << 6) + (ni << 4) + lq][0];
#pragma unroll
    for (int mi = 0; mi < 4; ++mi)
#pragma unroll
      for (int ni = 0; ni < 4; ++ni)
        acc[mi][ni] = __builtin_amdgcn_mfma_f32_16x16x32_bf16(af[mi], bfv[ni], acc[mi][ni], 0, 0, 0);
  }
#pragma unroll
  for (int ni = 0; ni < 4; ++ni) {
    const int col = n0 + (wn << 6) + (ni << 4) + lq;
    const float bs = be[(size_t)e * I_ + col];
#pragma unroll
    for (int mi = 0; mi < 4; ++mi) {
      const int rloc = (wm << 6) + (mi << 4) + (g << 2);
#pragma unroll
      for (int r = 0; r < 4; ++r) {
        const int tok = tokL[rloc + r];
        if (tok >= 0)
          inter[(size_t)tok * I_ + col] = f2bf(gelu_f(acc[mi][ni][r] + bs));
      }
    }
  }
}

// ---------- MFMA flash attention (bf16 fused-QKV input, bf16 ctx out) ----------
__global__ __launch_bounds__(256) void attn_mfma_kernel(
    const ushort* __restrict__ qkv, ushort* __restrict__ ctx)
{
  __shared__ __align__(16) ushort Ks[64 * 72];      // [key][d]
  __shared__ __align__(16) ushort Vt[64 * 72];      // [d][key]
  __shared__ __align__(16) ushort Ps[4][16 * 72];   // per-wave P [query][key]
  const int bid0 = blockIdx.x;
  const int bid  = ((bid0 & 7) << 7) + (bid0 >> 3);   // bijective XCD swizzle
  const int bh = bid >> 5, qt = bid & 31;
  const int b = bh >> 4, h = bh & 15;
  const int tid = threadIdx.x, w = tid >> 6, l = tid & 63;
  const int lq = l & 15, g = l >> 4;
  const size_t bS = (size_t)b * S_;
  const ushort* qb = qkv + bS * QKVLD + h * DH_;
  const ushort* kb = qb + 1024;
  const ushort* vb = qb + 2048;

  s8v qf0, qf1;
  {
    const ushort* qp = qb + (size_t)(qt * 64 + w * 16 + lq) * QKVLD;
    qf0 = *(const s8v*)(qp + (g << 3));
    qf1 = *(const s8v*)(qp + 32 + (g << 3));
  }

  f4 o0 = {0,0,0,0}, o1 = {0,0,0,0}, o2 = {0,0,0,0}, o3 = {0,0,0,0};
  float mrun = -3.0e38f, lrun = 0.f;

  const int skey = tid >> 2;           // staging: key row 0..63
  const int sd   = (tid & 3) << 4;     // staging: d start {0,16,32,48}

  for (int kt = 0; kt < 32; ++kt) {
    __syncthreads();
    {
      const ushort* kp = kb + (size_t)(kt * 64 + skey) * QKVLD + sd;
      *(s8v*)&Ks[skey * 72 + sd]     = *(const s8v*)(kp);
      *(s8v*)&Ks[skey * 72 + sd + 8] = *(const s8v*)(kp + 8);
      const ushort* vp = vb + (size_t)(kt * 64 + skey) * QKVLD + sd;
      const s8v v0 = *(const s8v*)(vp);
      const s8v v1 = *(const s8v*)(vp + 8);
#pragma unroll
      for (int ii = 0; ii < 8; ++ii) {
        Vt[(sd + ii) * 72 + skey]     = v0[ii];
        Vt[(sd + 8 + ii) * 72 + skey] = v1[ii];
      }
    }
    __syncthreads();

    // QK^T (swapped): lane l holds S[key=st*16+4g+r][query=lq]
    float s[16];
#pragma unroll
    for (int st = 0; st < 4; ++st) {
      f4 acc = {0, 0, 0, 0};
      const s8v ka0 = *(const s8v*)&Ks[(st * 16 + lq) * 72 + (g << 3)];
      const s8v ka1 = *(const s8v*)&Ks[(st * 16 + lq) * 72 + 32 + (g << 3)];
      acc = __builtin_amdgcn_mfma_f32_16x16x32_bf16(ka0, qf0, acc, 0, 0, 0);
      acc = __builtin_amdgcn_mfma_f32_16x16x32_bf16(ka1, qf1, acc, 0, 0, 0);
      s[st * 4 + 0] = acc[0] * 0.125f; s[st * 4 + 1] = acc[1] * 0.125f;
      s[st * 4 + 2] = acc[2] * 0.125f; s[st * 4 + 3] = acc[3] * 0.125f;
    }

    float tmax = s[0];
#pragma unroll
    for (int i = 1; i < 16; ++i) tmax = fmaxf(tmax, s[i]);
    tmax = fmaxf(tmax, __shfl_xor(tmax, 16));
    tmax = fmaxf(tmax, __shfl_xor(tmax, 32));
    const float mnew  = fmaxf(mrun, tmax);
    const float alpha = __expf(mrun - mnew);
    float psum = 0.f;
#pragma unroll
    for (int i = 0; i < 16; ++i) { s[i] = __expf(s[i] - mnew); psum += s[i]; }
    psum += __shfl_xor(psum, 16); psum += __shfl_xor(psum, 32);
    lrun = lrun * alpha + psum; mrun = mnew;

    f4 av;
    av[0] = __shfl(alpha, g * 4 + 0); av[1] = __shfl(alpha, g * 4 + 1);
    av[2] = __shfl(alpha, g * 4 + 2); av[3] = __shfl(alpha, g * 4 + 3);
    o0 *= av; o1 *= av; o2 *= av; o3 *= av;

    {
      ushort* pw = &Ps[w][lq * 72];
#pragma unroll
      for (int st = 0; st < 4; ++st) {
        *(u32*)&pw[st * 16 + g * 4 + 0] = pack_bf2(s[st * 4 + 0], s[st * 4 + 1]);
        *(u32*)&pw[st * 16 + g * 4 + 2] = pack_bf2(s[st * 4 + 2], s[st * 4 + 3]);
      }
    }
    asm volatile("s_waitcnt lgkmcnt(0)" ::: "memory");
    __builtin_amdgcn_sched_barrier(0);

#pragma unroll
    for (int ks = 0; ks < 2; ++ks) {
      const int kof = ks * 32 + (g << 3);
      const s8v pa = *(const s8v*)&Ps[w][lq * 72 + kof];
      const s8v v0 = *(const s8v*)&Vt[( 0 + lq) * 72 + kof];
      const s8v v1 = *(const s8v*)&Vt[(16 + lq) * 72 + kof];
      const s8v v2 = *(const s8v*)&Vt[(32 + lq) * 72 + kof];
      const s8v v3 = *(const s8v*)&Vt[(48 + lq) * 72 + kof];
      o0 = __builtin_amdgcn_mfma_f32_16x16x32_bf16(pa, v0, o0, 0, 0, 0);
      o1 = __builtin_amdgcn_mfma_f32_16x16x32_bf16(pa, v1, o1, 0, 0, 0);
      o2 = __builtin_amdgcn_mfma_f32_16x16x32_bf16(pa, v2, o2, 0, 0, 0);
      o3 = __builtin_amdgcn_mfma_f32_16x16x32_bf16(pa, v3, o3, 0, 0, 0);
    }
  }

  const float inv = 1.f / lrun;
#pragma unroll
  for (int r = 0; r < 4; ++r) {
    const float li = __shfl(inv, g * 4 + r);
    ushort* op = ctx + (bS + (size_t)(qt * 64 + w * 16 + g * 4 + r)) * H_ + h * DH_ + lq;
    op[0]  = f2bf(o0[r] * li);
    op[16] = f2bf(o1[r] * li);
    op[32] = f2bf(o2[r] * li);
    op[48] = f2bf(o3[r] * li);
  }
}

// ---------- residual add + LayerNorm (fp32 out, optional bf16 out) ----------
__global__ __launch_bounds__(256) void add_ln_kernel(
    const float* __restrict__ a, const float* __restrict__ r,
    const float* __restrict__ g, const float* __restrict__ bta,
    float* __restrict__ out, ushort* __restrict__ ob)
{
  const int row = blockIdx.x, tid = threadIdx.x;
  const size_t base = (size_t)row * H_;
  const float4 xa = *(const float4*)(a + base + (tid << 2));
  const float4 xr = *(const float4*)(r + base + (tid << 2));
  float4 x = make_float4(xa.x + xr.x, xa.y + xr.y, xa.z + xr.z, xa.w + xr.w);
  float s  = x.x + x.y + x.z + x.w;
  float ss = x.x * x.x + x.y * x.y + x.z * x.z + x.w * x.w;
#pragma unroll
  for (int off = 1; off < 64; off <<= 1) { s += __shfl_xor(s, off); ss += __shfl_xor(ss, off); }
  __shared__ float red[8];
  const int w = tid >> 6, ln = tid & 63;
  if (ln == 0) { red[w] = s; red[4 + w] = ss; }
  __syncthreads();
  const float S  = red[0] + red[1] + red[2] + red[3];
  const float SS = red[4] + red[5] + red[6] + red[7];
  const float mu  = S * (1.f / 1024.f);
  const float var = fmaxf(SS * (1.f / 1024.f) - mu * mu, 0.f);
  const float inv = rsqrtf(var + LN_EPS);
  const float4 gg = *(const float4*)&g[tid << 2];
  const float4 bb = *(const float4*)&bta[tid << 2];
  float4 y;
  y.x = (x.x - mu) * inv * gg.x + bb.x;
  y.y = (x.y - mu) * inv * gg.y + bb.y;
  y.z = (x.z - mu) * inv * gg.z + bb.z;
  y.w = (x.w - mu) * inv * gg.w + bb.w;
  *(float4*)&out[base + (tid << 2)] = y;
  if (ob) {
    ushort4 u;
    u.x = f2bf(y.x); u.y = f2bf(y.y); u.z = f2bf(y.z); u.w = f2bf(y.w);
    *(ushort4*)&ob[base + (tid << 2)] = u;
  }
}

// ---------- router ----------
__global__ __launch_bounds__(64) void router_kernel(
    const float* __restrict__ x, const float* __restrict__ rw,
    int* __restrict__ idx, int* __restrict__ cnt)
{
  const int t = blockIdx.x, lane = threadIdx.x;
  float acc[8] = {0.f};
  for (int c = 0; c < H_; c += 64) {
    const float xv = x[(size_t)t * H_ + c + lane];
    const float* wr = rw + (size_t)(c + lane) * E_;
    const float4 w0 = *(const float4*)wr;
    const float4 w1 = *(const float4*)(wr + 4);
    acc[0] += xv * w0.x; acc[1] += xv * w0.y; acc[2] += xv * w0.z; acc[3] += xv * w0.w;
    acc[4] += xv * w1.x; acc[5] += xv * w1.y; acc[6] += xv * w1.z; acc[7] += xv * w1.w;
  }
#pragma unroll
  for (int e = 0; e < E_; ++e) {
    float s = acc[e];
#pragma unroll
    for (int off = 1; off < 64; off <<= 1) s += __shfl_xor(s, off);
    acc[e] = s;
  }
  if (lane == 0) {
    int be_ = 0; float bv = acc[0];
#pragma unroll
    for (int e = 1; e < E_; ++e) if (acc[e] > bv) { bv = acc[e]; be_ = e; }
    idx[t] = be_;
    atomicAdd(&cnt[be_], 1);
  }
}

__global__ void init_kernel(int* cnt) { if (threadIdx.x < E_) cnt[threadIdx.x] = 0; }

__global__ void scan_kernel(const int* __restrict__ cnt, int* __restrict__ offs,
                            int* __restrict__ cursor, int* __restrict__ tb)
{
  int o = 0, tt = 0;
  for (int e = 0; e < E_; ++e) {
    offs[e] = o; cursor[e] = o; tb[e] = tt;
    o += cnt[e]; tt += (cnt[e] + 127) >> 7;
  }
  tb[E_] = tt;
}

__global__ __launch_bounds__(256) void scatter_kernel(
    const int* __restrict__ idx, int* __restrict__ cursor, int* __restrict__ lists)
{
  const int t = blockIdx.x * 256 + threadIdx.x;
  if (t < N_) {
    const int e = idx[t];
    const int p = atomicAdd(&cursor[e], 1);
    lists[p] = t;
  }
}

// ---------- launch ----------
extern "C" void kernel_launch(void* const* d_in, const int* in_sizes, int n_in,
                              void* d_out, int out_size, void* d_ws, size_t ws_size,
                              hipStream_t stream) {
  const float* x   = (const float*)d_in[0];
  const float* Wq  = (const float*)d_in[1];
  const float* bq  = (const float*)d_in[2];
  const float* Wk  = (const float*)d_in[3];
  const float* bk  = (const float*)d_in[4];
  const float* Wv  = (const float*)d_in[5];
  const float* bv  = (const float*)d_in[6];
  const float* Wao = (const float*)d_in[7];
  const float* bao = (const float*)d_in[8];
  const float* g1  = (const float*)d_in[9];
  const float* b1  = (const float*)d_in[10];
  const float* rw  = (const float*)d_in[11];
  const float* We  = (const float*)d_in[12];
  const float* be  = (const float*)d_in[13];
  const float* Wo  = (const float*)d_in[14];
  const float* bo  = (const float*)d_in[15];
  const float* g2  = (const float*)d_in[16];
  const float* b2  = (const float*)d_in[17];
  float* out = (float*)d_out;

  char* p = (char*)d_ws;
  int* idx    = (int*)p; p += (size_t)N_ * 4;
  int* cnt    = (int*)p; p += 8 * 4;
  int* offs   = (int*)p; p += 8 * 4;
  int* cursor = (int*)p; p += 8 * 4;
  int* tb     = (int*)p; p += 16 * 4;
  int* lists  = (int*)p; p += (size_t)N_ * 4;
  p = (char*)(((uintptr_t)p + 255) & ~(uintptr_t)255);
  const size_t NH = (size_t)N_ * H_;
  ushort* xb     = (ushort*)p; p += NH * 2;                 // x bf16
  ushort* qkvb   = (ushort*)p; p += (size_t)N_ * QKVLD * 2; // fused qkv bf16
  ushort* ctxb   = (ushort*)p; p += NH * 2;                 // attn ctx bf16
  float*  t1     = (float*)p;  p += NH * 4;                 // fp32 pre-LN buffer
  float*  attn   = (float*)p;  p += NH * 4;                 // LN1 out fp32
  ushort* attnb  = (ushort*)p; p += NH * 2;                 // LN1 out bf16
  ushort* interb = (ushort*)p; p += (size_t)N_ * I_ * 2;    // MoE inter bf16
  ushort* WqkvT  = (ushort*)p; p += (size_t)QKVLD * H_ * 2; // [3072][1024]
  ushort* WaoT   = (ushort*)p; p += (size_t)H_ * H_ * 2;    // [1024][1024]
  ushort* WoT    = (ushort*)p; p += (size_t)H_ * I_ * 2;    // [1024][4096]
  ushort* WeT    = (ushort*)p; p += (size_t)E_ * I_ * H_ * 2; // [8][4096][1024]
  float*  bqkv   = (float*)p;  p += QKVLD * 4;

  const dim3 blk(256);

  init_kernel<<<1, 64, 0, stream>>>(cnt);
  cvt_bf16_kernel<<<(N_ * H_ / 8 + 255) / 256, blk, 0, stream>>>(x, xb, N_ * H_ / 8);
  concat3_kernel<<<QKVLD / 256, blk, 0, stream>>>(bq, bk, bv, bqkv);
  transpose_cvt_kernel<<<dim3(32, 32, 1), blk, 0, stream>>>(Wq, WqkvT, H_, H_);
  transpose_cvt_kernel<<<dim3(32, 32, 1), blk, 0, stream>>>(Wk, WqkvT + (size_t)1024 * H_, H_, H_);
  transpose_cvt_kernel<<<dim3(32, 32, 1), blk, 0, stream>>>(Wv, WqkvT + (size_t)2048 * H_, H_, H_);
  transpose_cvt_kernel<<<dim3(32, 32, 1), blk, 0, stream>>>(Wao, WaoT, H_, H_);
  transpose_cvt_kernel<<<dim3(32, 128, 1), blk, 0, stream>>>(Wo, WoT, I_, H_);
  transpose_cvt_kernel<<<dim3(128, 32, 8), blk, 0, stream>>>(We, WeT, H_, I_);

  gemm_mfma_kernel<true><<<dim3(QKVLD / 128, N_ / 128), blk, 0, stream>>>(
      xb, WqkvT, bqkv, qkvb, N_, QKVLD, H_);
  attn_mfma_kernel<<<1024, blk, 0, stream>>>(qkvb, ctxb);
  gemm_mfma_kernel<false><<<dim3(H_ / 128, N_ / 128), blk, 0, stream>>>(
      ctxb, WaoT, bao, t1, N_, H_, H_);
  add_ln_kernel<<<N_, blk, 0, stream>>>(t1, x, g1, b1, attn, attnb);
  router_kernel<<<N_, 64, 0, stream>>>(attn, rw, idx, cnt);
  scan_kernel<<<1, 1, 0, stream>>>(cnt, offs, cursor, tb);
  scatter_kernel<<<N_ / 256, blk, 0, stream>>>(idx, cursor, lists);
  moe_mfma_kernel<<<dim3(I_ / 128, N_ / 128 + E_), blk, 0, stream>>>(
      attnb, WeT, be, lists, offs, cnt, tb, interb);
  gemm_mfma_kernel<false><<<dim3(H_ / 128, N_ / 128), blk, 0, stream>>>(
      interb, WoT, bo, t1, N_, H_, I_);
  add_ln_kernel<<<N_, blk, 0, stream>>>(t1, attn, g2, b2, out, (ushort*)nullptr);
}

// Round 6
// 545.871 us; speedup vs baseline: 8.5960x; 1.1295x over previous
//
#include <hip/hip_runtime.h>
#include <hip/hip_bf16.h>
#include <cstdint>

#define H_  1024
#define NH_ 16
#define DH_ 64
#define I_  4096
#define E_  8
#define B_  2
#define S_  2048
#define N_  4096        // B_*S_
#define QKVLD 3072      // fused qkv row stride
#define LN_EPS 1e-12f

typedef __attribute__((ext_vector_type(4))) float f4;
typedef __attribute__((ext_vector_type(8))) short s8v;
typedef unsigned int u32;

// ---------- helpers ----------
__device__ __forceinline__ float bf2f(unsigned short u) {
  union { unsigned int i; float f; } c; c.i = ((unsigned int)u) << 16; return c.f;
}
__device__ __forceinline__ unsigned short f2bf(float f) {
  __hip_bfloat16 h = __float2bfloat16(f);
  return *reinterpret_cast<unsigned short*>(&h);
}
__device__ __forceinline__ u32 pack_bf2(float a, float b) {
  return (u32)f2bf(a) | ((u32)f2bf(b) << 16);
}
__device__ __forceinline__ float gelu_f(float x) {
  return 0.5f * x * (1.0f + erff(x * 0.70710678118f));   // exact GELU
}
__device__ __forceinline__ void gload16(const void* g, void* l) {
  __builtin_amdgcn_global_load_lds(
      (const __attribute__((address_space(1))) void*)g,
      (__attribute__((address_space(3))) void*)l, 16, 0, 0);
}

// ---------- fp32 -> bf16 elementwise ----------
__global__ __launch_bounds__(256) void cvt_bf16_kernel(
    const float* __restrict__ in, ushort* __restrict__ out, int n8)
{
  const int t = blockIdx.x * 256 + threadIdx.x;
  if (t >= n8) return;
  const f4 x0 = *(const f4*)(in + (size_t)t * 8);
  const f4 x1 = *(const f4*)(in + (size_t)t * 8 + 4);
  s8v o;
#pragma unroll
  for (int j = 0; j < 4; ++j) { o[j] = (short)f2bf(x0[j]); o[4 + j] = (short)f2bf(x1[j]); }
  *(s8v*)(out + (size_t)t * 8) = o;
}

// ---------- fp32 [R][C] -> bf16 [C][R] transpose ----------
__global__ __launch_bounds__(256) void transpose_cvt_kernel(
    const float* __restrict__ in, ushort* __restrict__ out, int R, int C)
{
  __shared__ float tile[32][33];
  const size_t zo = (size_t)blockIdx.z * R * C;
  const int bx = blockIdx.x << 5, by = blockIdx.y << 5;
  const int tx = threadIdx.x & 31, ty = threadIdx.x >> 5;   // ty 0..7
  const float* ip = in + zo + (size_t)by * C + bx;
#pragma unroll
  for (int i = 0; i < 4; ++i)
    tile[ty + 8 * i][tx] = ip[(size_t)(ty + 8 * i) * C + tx];
  __syncthreads();
  ushort* op = out + zo + (size_t)bx * R + by;
#pragma unroll
  for (int i = 0; i < 4; ++i)
    op[(size_t)(ty + 8 * i) * R + tx] = f2bf(tile[tx][ty + 8 * i]);
}

__global__ void concat3_kernel(const float* a, const float* b, const float* c,
                               float* __restrict__ o)
{
  const int t = blockIdx.x * 256 + threadIdx.x;   // 3072 total
  if (t < 1024) o[t] = a[t];
  else if (t < 2048) o[t] = b[t - 1024];
  else o[t] = c[t - 2048];
}

// ---------- MFMA GEMM: C = A * W + bias, 2-phase double-buffered prefetch ----
// A [M,K] bf16 row-major, Bt = W^T [N,K] bf16 row-major. 128x128 tile, BK=32.
// KSPLIT>1: blockIdx.z covers K/KSPLIT; fp32 partials at Cout + z*M*N (bias in z0).
template <bool BF16OUT, int KSPLIT>
__global__ __launch_bounds__(256, 3) void gemm_mfma_kernel(
    const ushort* __restrict__ A, const ushort* __restrict__ Bt,
    const float* __restrict__ bias, void* __restrict__ Cout,
    const int M, const int N, const int K)
{
  __shared__ __align__(16) ushort Asm[2][4][128][8];
  __shared__ __align__(16) ushort Bsm[2][4][128][8];
  const int tid = threadIdx.x;
  const int w = tid >> 6, l = tid & 63;
  const int lq = l & 15, g = l >> 4;
  const int wm = w >> 1, wn = w & 1;
  // XCD-aware bijective tile swizzle (nwg % 8 == 0 for all launches)
  const int nbx = N >> 7;
  const int nwg = nbx * (M >> 7);
  int id = blockIdx.y * nbx + blockIdx.x;
  id = (id & 7) * (nwg >> 3) + (id >> 3);
  const int m0 = (id / nbx) << 7, n0 = (id % nbx) << 7;
  const int Kspan = K / KSPLIT;
  const int kbase = (KSPLIT > 1) ? blockIdx.z * Kspan : 0;

  const ushort* a0 = A + (size_t)(m0 + l) * K + kbase + (w << 3);
  const ushort* a1 = a0 + (size_t)64 * K;
  const ushort* b0 = Bt + (size_t)(n0 + l) * K + kbase + (w << 3);
  const ushort* b1 = b0 + (size_t)64 * K;

  f4 acc[4][4] = {};
  const int nt = Kspan >> 5;
  // prologue: stage tile 0 -> buf 0
  gload16(a0, &Asm[0][w][0][0]);  gload16(a1, &Asm[0][w][64][0]);
  gload16(b0, &Bsm[0][w][0][0]);  gload16(b1, &Bsm[0][w][64][0]);
  __syncthreads();
  int cur = 0;
  for (int t = 0; t < nt; ++t) {
    if (t + 1 < nt) {                      // issue next tile before compute
      const int kt = (t + 1) << 5;
      gload16(a0 + kt, &Asm[cur ^ 1][w][0][0]);
      gload16(a1 + kt, &Asm[cur ^ 1][w][64][0]);
      gload16(b0 + kt, &Bsm[cur ^ 1][w][0][0]);
      gload16(b1 + kt, &Bsm[cur ^ 1][w][64][0]);
    }
    s8v af[4], bfv[4];
#pragma unroll
    for (int mi = 0; mi < 4; ++mi)
      af[mi] = *(const s8v*)&Asm[cur][g][(wm << 6) + (mi << 4) + lq][0];
#pragma unroll
    for (int ni = 0; ni < 4; ++ni)
      bfv[ni] = *(const s8v*)&Bsm[cur][g][(wn << 6) + (ni << 4) + lq][0];
#pragma unroll
    for (int mi = 0; mi < 4; ++mi)
#pragma unroll
      for (int ni = 0; ni < 4; ++ni)
        acc[mi][ni] = __builtin_amdgcn_mfma_f32_16x16x32_bf16(af[mi], bfv[ni], acc[mi][ni], 0, 0, 0);
    __syncthreads();                       // drains vmcnt(0): next buf ready
    cur ^= 1;
  }
  float* outf = (float*)Cout + (size_t)blockIdx.z * M * N;
#pragma unroll
  for (int ni = 0; ni < 4; ++ni) {
    const int col = n0 + (wn << 6) + (ni << 4) + lq;
    const float bs = (KSPLIT == 1 || blockIdx.z == 0) ? bias[col] : 0.f;
#pragma unroll
    for (int mi = 0; mi < 4; ++mi) {
      const int row = m0 + (wm << 6) + (mi << 4) + (g << 2);
#pragma unroll
      for (int r = 0; r < 4; ++r) {
        const float val = acc[mi][ni][r] + bs;
        if constexpr (BF16OUT) ((ushort*)Cout)[(size_t)(row + r) * N + col] = f2bf(val);
        else                   outf[(size_t)(row + r) * N + col] = val;
      }
    }
  }
}

// ---------- MoE expert GEMM (MFMA, prefetched) ----------
__global__ __launch_bounds__(256, 3) void moe_mfma_kernel(
    const ushort* __restrict__ X, const ushort* __restrict__ WeT,
    const float* __restrict__ be, const int* __restrict__ lists,
    const int* __restrict__ offs, const int* __restrict__ cnt,
    const int* __restrict__ tb, ushort* __restrict__ inter)
{
  __shared__ __align__(16) ushort Asm[2][4][128][8];
  __shared__ __align__(16) ushort Bsm[2][4][128][8];
  __shared__ int tokL[128];
  const int by = blockIdx.y;
  if (by >= tb[E_]) return;
  int e = 0;
#pragma unroll
  for (int t = 1; t < E_; ++t) if (by >= tb[t]) e = t;
  const int rt = by - tb[e];
  const int base = offs[e] + (rt << 7);
  const int nrows = cnt[e] - (rt << 7);
  const int tid = threadIdx.x;
  if (tid < 128) tokL[tid] = (tid < nrows) ? lists[base + tid] : -1;
  const int w = tid >> 6, l = tid & 63;
  const int lq = l & 15, g = l >> 4;
  const int wm = w >> 1, wn = w & 1;
  const int n0 = blockIdx.x << 7;
  const int t0 = (l < nrows) ? lists[base + l] : lists[base];
  const int t1 = (64 + l < nrows) ? lists[base + 64 + l] : lists[base];
  const ushort* a0 = X + (size_t)t0 * H_ + (w << 3);
  const ushort* a1 = X + (size_t)t1 * H_ + (w << 3);
  const ushort* Wp = WeT + (size_t)e * I_ * H_;
  const ushort* b0 = Wp + (size_t)(n0 + l) * H_ + (w << 3);
  const ushort* b1 = b0 + (size_t)64 * H_;

  f4 acc[4][4] = {};
  gload16(a0, &Asm[0][w][0][0]);  gload16(a1, &Asm[0][w][64][0]);
  gload16(b0, &Bsm[0][w][0][0]);  gload16(b1, &Bsm[0][w][64][0]);
  __syncthreads();
  int cur = 0;
  for (int t = 0; t < 32; ++t) {
    if (t + 1 < 32) {
      const int kt = (t + 1) << 5;
      gload16(a0 + kt, &Asm[cur ^ 1][w][0][0]);
      gload16(a1 + kt, &Asm[cur ^ 1][w][64][0]);
      gload16(b0 + kt, &Bsm[cur ^ 1][w][0][0]);
      gload16(b1 + kt, &Bsm[cur ^ 1][w][64][0]);
    }
    s8v af[4], bfv[4];
#pragma unroll
    for (int mi = 0; mi < 4; ++mi)
      af[mi] = *(const s8v*)&Asm[cur][g][(wm << 6) + (mi << 4) + lq][0];
#pragma unroll
    for (int ni = 0; ni < 4; ++ni)
      bfv[ni] = *(const s8v*)&Bsm[cur][g][(wn << 6) + (ni << 4) + lq][0];
#pragma unroll
    for (int mi = 0; mi < 4; ++mi)
#pragma unroll
      for (int ni = 0; ni < 4; ++ni)
        acc[mi][ni] = __builtin_amdgcn_mfma_f32_16x16x32_bf16(af[mi], bfv[ni], acc[mi][ni], 0, 0, 0);
    __syncthreads();
    cur ^= 1;
  }
#pragma unroll
  for (int ni = 0; ni < 4; ++ni) {
    const int col = n0 + (wn << 6) + (ni << 4) + lq;
    const float bs = be[(size_t)e * I_ + col];
#pragma unroll
    for (int mi = 0; mi < 4; ++mi) {
      const int rloc = (wm << 6) + (mi << 4) + (g << 2);
#pragma unroll
      for (int r = 0; r < 4; ++r) {
        const int tok = tokL[rloc + r];
        if (tok >= 0)
          inter[(size_t)tok * I_ + col] = f2bf(gelu_f(acc[mi][ni][r] + bs));
      }
    }
  }
}

// ---------- MFMA flash attention (bf16 fused-QKV input, bf16 ctx out) ----------
__global__ __launch_bounds__(256) void attn_mfma_kernel(
    const ushort* __restrict__ qkv, ushort* __restrict__ ctx)
{
  __shared__ __align__(16) ushort Ks[64 * 72];      // [key][d]
  __shared__ __align__(16) ushort Vt[64 * 72];      // [d][key]
  __shared__ __align__(16) ushort Ps[4][16 * 72];   // per-wave P [query][key]
  const int bid0 = blockIdx.x;
  const int bid  = ((bid0 & 7) << 7) + (bid0 >> 3);   // bijective XCD swizzle
  const int bh = bid >> 5, qt = bid & 31;
  const int b = bh >> 4, h = bh & 15;
  const int tid = threadIdx.x, w = tid >> 6, l = tid & 63;
  const int lq = l & 15, g = l >> 4;
  const size_t bS = (size_t)b * S_;
  const ushort* qb = qkv + bS * QKVLD + h * DH_;
  const ushort* kb = qb + 1024;
  const ushort* vb = qb + 2048;

  s8v qf0, qf1;
  {
    const ushort* qp = qb + (size_t)(qt * 64 + w * 16 + lq) * QKVLD;
    qf0 = *(const s8v*)(qp + (g << 3));
    qf1 = *(const s8v*)(qp + 32 + (g << 3));
  }

  f4 o0 = {0,0,0,0}, o1 = {0,0,0,0}, o2 = {0,0,0,0}, o3 = {0,0,0,0};
  float mrun = -3.0e38f, lrun = 0.f;

  const int skey = tid >> 2;           // staging: key row 0..63
  const int sd   = (tid & 3) << 4;     // staging: d start {0,16,32,48}

  for (int kt = 0; kt < 32; ++kt) {
    __syncthreads();
    {
      const ushort* kp = kb + (size_t)(kt * 64 + skey) * QKVLD + sd;
      *(s8v*)&Ks[skey * 72 + sd]     = *(const s8v*)(kp);
      *(s8v*)&Ks[skey * 72 + sd + 8] = *(const s8v*)(kp + 8);
      const ushort* vp = vb + (size_t)(kt * 64 + skey) * QKVLD + sd;
      const s8v v0 = *(const s8v*)(vp);
      const s8v v1 = *(const s8v*)(vp + 8);
#pragma unroll
      for (int ii = 0; ii < 8; ++ii) {
        Vt[(sd + ii) * 72 + skey]     = v0[ii];
        Vt[(sd + 8 + ii) * 72 + skey] = v1[ii];
      }
    }
    __syncthreads();

    // QK^T (swapped): lane l holds S[key=st*16+4g+r][query=lq]
    float s[16];
#pragma unroll
    for (int st = 0; st < 4; ++st) {
      f4 acc = {0, 0, 0, 0};
      const s8v ka0 = *(const s8v*)&Ks[(st * 16 + lq) * 72 + (g << 3)];
      const s8v ka1 = *(const s8v*)&Ks[(st * 16 + lq) * 72 + 32 + (g << 3)];
      acc = __builtin_amdgcn_mfma_f32_16x16x32_bf16(ka0, qf0, acc, 0, 0, 0);
      acc = __builtin_amdgcn_mfma_f32_16x16x32_bf16(ka1, qf1, acc, 0, 0, 0);
      s[st * 4 + 0] = acc[0] * 0.125f; s[st * 4 + 1] = acc[1] * 0.125f;
      s[st * 4 + 2] = acc[2] * 0.125f; s[st * 4 + 3] = acc[3] * 0.125f;
    }

    float tmax = s[0];
#pragma unroll
    for (int i = 1; i < 16; ++i) tmax = fmaxf(tmax, s[i]);
    tmax = fmaxf(tmax, __shfl_xor(tmax, 16));
    tmax = fmaxf(tmax, __shfl_xor(tmax, 32));
    const float mnew  = fmaxf(mrun, tmax);
    const float alpha = __expf(mrun - mnew);
    float psum = 0.f;
#pragma unroll
    for (int i = 0; i < 16; ++i) { s[i] = __expf(s[i] - mnew); psum += s[i]; }
    psum += __shfl_xor(psum, 16); psum += __shfl_xor(psum, 32);
    lrun = lrun * alpha + psum; mrun = mnew;

    f4 av;
    av[0] = __shfl(alpha, g * 4 + 0); av[1] = __shfl(alpha, g * 4 + 1);
    av[2] = __shfl(alpha, g * 4 + 2); av[3] = __shfl(alpha, g * 4 + 3);
    o0 *= av; o1 *= av; o2 *= av; o3 *= av;

    {
      ushort* pw = &Ps[w][lq * 72];
#pragma unroll
      for (int st = 0; st < 4; ++st) {
        *(u32*)&pw[st * 16 + g * 4 + 0] = pack_bf2(s[st * 4 + 0], s[st * 4 + 1]);
        *(u32*)&pw[st * 16 + g * 4 + 2] = pack_bf2(s[st * 4 + 2], s[st * 4 + 3]);
      }
    }
    asm volatile("s_waitcnt lgkmcnt(0)" ::: "memory");
    __builtin_amdgcn_sched_barrier(0);

#pragma unroll
    for (int ks = 0; ks < 2; ++ks) {
      const int kof = ks * 32 + (g << 3);
      const s8v pa = *(const s8v*)&Ps[w][lq * 72 + kof];
      const s8v v0 = *(const s8v*)&Vt[( 0 + lq) * 72 + kof];
      const s8v v1 = *(const s8v*)&Vt[(16 + lq) * 72 + kof];
      const s8v v2 = *(const s8v*)&Vt[(32 + lq) * 72 + kof];
      const s8v v3 = *(const s8v*)&Vt[(48 + lq) * 72 + kof];
      o0 = __builtin_amdgcn_mfma_f32_16x16x32_bf16(pa, v0, o0, 0, 0, 0);
      o1 = __builtin_amdgcn_mfma_f32_16x16x32_bf16(pa, v1, o1, 0, 0, 0);
      o2 = __builtin_amdgcn_mfma_f32_16x16x32_bf16(pa, v2, o2, 0, 0, 0);
      o3 = __builtin_amdgcn_mfma_f32_16x16x32_bf16(pa, v3, o3, 0, 0, 0);
    }
  }

  const float inv = 1.f / lrun;
#pragma unroll
  for (int r = 0; r < 4; ++r) {
    const float li = __shfl(inv, g * 4 + r);
    ushort* op = ctx + (bS + (size_t)(qt * 64 + w * 16 + g * 4 + r)) * H_ + h * DH_ + lq;
    op[0]  = f2bf(o0[r] * li);
    op[16] = f2bf(o1[r] * li);
    op[32] = f2bf(o2[r] * li);
    op[48] = f2bf(o3[r] * li);
  }
}

// ---------- P-partial sum + residual add + LayerNorm ----------
template <int P>
__global__ __launch_bounds__(256) void add_ln_kernel(
    const float* __restrict__ a, const float* __restrict__ r,
    const float* __restrict__ g, const float* __restrict__ bta,
    float* __restrict__ out, ushort* __restrict__ ob)
{
  const int row = blockIdx.x, tid = threadIdx.x;
  const size_t base = (size_t)row * H_;
  const float4 xr = *(const float4*)(r + base + (tid << 2));
  float4 x = xr;
#pragma unroll
  for (int pp = 0; pp < P; ++pp) {
    const float4 xa = *(const float4*)(a + (size_t)pp * N_ * H_ + base + (tid << 2));
    x.x += xa.x; x.y += xa.y; x.z += xa.z; x.w += xa.w;
  }
  float s  = x.x + x.y + x.z + x.w;
  float ss = x.x * x.x + x.y * x.y + x.z * x.z + x.w * x.w;
#pragma unroll
  for (int off = 1; off < 64; off <<= 1) { s += __shfl_xor(s, off); ss += __shfl_xor(ss, off); }
  __shared__ float red[8];
  const int w = tid >> 6, ln = tid & 63;
  if (ln == 0) { red[w] = s; red[4 + w] = ss; }
  __syncthreads();
  const float S  = red[0] + red[1] + red[2] + red[3];
  const float SS = red[4] + red[5] + red[6] + red[7];
  const float mu  = S * (1.f / 1024.f);
  const float var = fmaxf(SS * (1.f / 1024.f) - mu * mu, 0.f);
  const float inv = rsqrtf(var + LN_EPS);
  const float4 gg = *(const float4*)&g[tid << 2];
  const float4 bb = *(const float4*)&bta[tid << 2];
  float4 y;
  y.x = (x.x - mu) * inv * gg.x + bb.x;
  y.y = (x.y - mu) * inv * gg.y + bb.y;
  y.z = (x.z - mu) * inv * gg.z + bb.z;
  y.w = (x.w - mu) * inv * gg.w + bb.w;
  *(float4*)&out[base + (tid << 2)] = y;
  if (ob) {
    ushort4 u;
    u.x = f2bf(y.x); u.y = f2bf(y.y); u.z = f2bf(y.z); u.w = f2bf(y.w);
    *(ushort4*)&ob[base + (tid << 2)] = u;
  }
}

// ---------- router ----------
__global__ __launch_bounds__(64) void router_kernel(
    const float* __restrict__ x, const float* __restrict__ rw,
    int* __restrict__ idx, int* __restrict__ cnt)
{
  const int t = blockIdx.x, lane = threadIdx.x;
  float acc[8] = {0.f};
  for (int c = 0; c < H_; c += 64) {
    const float xv = x[(size_t)t * H_ + c + lane];
    const float* wr = rw + (size_t)(c + lane) * E_;
    const float4 w0 = *(const float4*)wr;
    const float4 w1 = *(const float4*)(wr + 4);
    acc[0] += xv * w0.x; acc[1] += xv * w0.y; acc[2] += xv * w0.z; acc[3] += xv * w0.w;
    acc[4] += xv * w1.x; acc[5] += xv * w1.y; acc[6] += xv * w1.z; acc[7] += xv * w1.w;
  }
#pragma unroll
  for (int e = 0; e < E_; ++e) {
    float s = acc[e];
#pragma unroll
    for (int off = 1; off < 64; off <<= 1) s += __shfl_xor(s, off);
    acc[e] = s;
  }
  if (lane == 0) {
    int be_ = 0; float bv = acc[0];
#pragma unroll
    for (int e = 1; e < E_; ++e) if (acc[e] > bv) { bv = acc[e]; be_ = e; }
    idx[t] = be_;
    atomicAdd(&cnt[be_], 1);
  }
}

__global__ void init_kernel(int* cnt) { if (threadIdx.x < E_) cnt[threadIdx.x] = 0; }

__global__ void scan_kernel(const int* __restrict__ cnt, int* __restrict__ offs,
                            int* __restrict__ cursor, int* __restrict__ tb)
{
  int o = 0, tt = 0;
  for (int e = 0; e < E_; ++e) {
    offs[e] = o; cursor[e] = o; tb[e] = tt;
    o += cnt[e]; tt += (cnt[e] + 127) >> 7;
  }
  tb[E_] = tt;
}

__global__ __launch_bounds__(256) void scatter_kernel(
    const int* __restrict__ idx, int* __restrict__ cursor, int* __restrict__ lists)
{
  const int t = blockIdx.x * 256 + threadIdx.x;
  if (t < N_) {
    const int e = idx[t];
    const int p = atomicAdd(&cursor[e], 1);
    lists[p] = t;
  }
}

// ---------- launch ----------
extern "C" void kernel_launch(void* const* d_in, const int* in_sizes, int n_in,
                              void* d_out, int out_size, void* d_ws, size_t ws_size,
                              hipStream_t stream) {
  const float* x   = (const float*)d_in[0];
  const float* Wq  = (const float*)d_in[1];
  const float* bq  = (const float*)d_in[2];
  const float* Wk  = (const float*)d_in[3];
  const float* bk  = (const float*)d_in[4];
  const float* Wv  = (const float*)d_in[5];
  const float* bv  = (const float*)d_in[6];
  const float* Wao = (const float*)d_in[7];
  const float* bao = (const float*)d_in[8];
  const float* g1  = (const float*)d_in[9];
  const float* b1  = (const float*)d_in[10];
  const float* rw  = (const float*)d_in[11];
  const float* We  = (const float*)d_in[12];
  const float* be  = (const float*)d_in[13];
  const float* Wo  = (const float*)d_in[14];
  const float* bo  = (const float*)d_in[15];
  const float* g2  = (const float*)d_in[16];
  const float* b2  = (const float*)d_in[17];
  float* out = (float*)d_out;

  char* p = (char*)d_ws;
  int* idx    = (int*)p; p += (size_t)N_ * 4;
  int* cnt    = (int*)p; p += 8 * 4;
  int* offs   = (int*)p; p += 8 * 4;
  int* cursor = (int*)p; p += 8 * 4;
  int* tb     = (int*)p; p += 16 * 4;
  int* lists  = (int*)p; p += (size_t)N_ * 4;
  p = (char*)(((uintptr_t)p + 255) & ~(uintptr_t)255);
  const size_t NH = (size_t)N_ * H_;
  ushort* xb     = (ushort*)p; p += NH * 2;                 // x bf16
  ushort* qkvb   = (ushort*)p;                              // fused qkv bf16 ...
  float*  woPart = (float*)p;  p += (size_t)N_ * QKVLD * 2; // ... reused: Wo fp32 partials x2
  ushort* ctxb   = (ushort*)p; p += NH * 2;                 // attn ctx bf16 (tail of woPart)
  float*  attn   = (float*)p;  p += NH * 4;                 // LN1 out fp32
  ushort* attnb  = (ushort*)p; p += NH * 2;                 // LN1 out bf16
  ushort* interb = (ushort*)p;                              // MoE inter bf16 ...
  float*  aoPart = (float*)p;  p += (size_t)N_ * I_ * 2;    // ... reused: AO fp32 partials x2
  ushort* WqkvT  = (ushort*)p; p += (size_t)QKVLD * H_ * 2; // [3072][1024]
  ushort* WaoT   = (ushort*)p; p += (size_t)H_ * H_ * 2;    // [1024][1024]
  ushort* WoT    = (ushort*)p; p += (size_t)H_ * I_ * 2;    // [1024][4096]
  ushort* WeT    = (ushort*)p; p += (size_t)E_ * I_ * H_ * 2; // [8][4096][1024]
  float*  bqkv   = (float*)p;  p += QKVLD * 4;

  const dim3 blk(256);

  init_kernel<<<1, 64, 0, stream>>>(cnt);
  cvt_bf16_kernel<<<(N_ * H_ / 8 + 255) / 256, blk, 0, stream>>>(x, xb, N_ * H_ / 8);
  concat3_kernel<<<QKVLD / 256, blk, 0, stream>>>(bq, bk, bv, bqkv);
  transpose_cvt_kernel<<<dim3(32, 32, 1), blk, 0, stream>>>(Wq, WqkvT, H_, H_);
  transpose_cvt_kernel<<<dim3(32, 32, 1), blk, 0, stream>>>(Wk, WqkvT + (size_t)1024 * H_, H_, H_);
  transpose_cvt_kernel<<<dim3(32, 32, 1), blk, 0, stream>>>(Wv, WqkvT + (size_t)2048 * H_, H_, H_);
  transpose_cvt_kernel<<<dim3(32, 32, 1), blk, 0, stream>>>(Wao, WaoT, H_, H_);
  transpose_cvt_kernel<<<dim3(32, 128, 1), blk, 0, stream>>>(Wo, WoT, I_, H_);
  transpose_cvt_kernel<<<dim3(128, 32, 8), blk, 0, stream>>>(We, WeT, H_, I_);

  gemm_mfma_kernel<true, 1><<<dim3(QKVLD / 128, N_ / 128), blk, 0, stream>>>(
      xb, WqkvT, bqkv, qkvb, N_, QKVLD, H_);
  attn_mfma_kernel<<<1024, blk, 0, stream>>>(qkvb, ctxb);
  gemm_mfma_kernel<false, 2><<<dim3(H_ / 128, N_ / 128, 2), blk, 0, stream>>>(
      ctxb, WaoT, bao, aoPart, N_, H_, H_);
  add_ln_kernel<2><<<N_, blk, 0, stream>>>(aoPart, x, g1, b1, attn, attnb);
  router_kernel<<<N_, 64, 0, stream>>>(attn, rw, idx, cnt);
  scan_kernel<<<1, 1, 0, stream>>>(cnt, offs, cursor, tb);
  scatter_kernel<<<N_ / 256, blk, 0, stream>>>(idx, cursor, lists);
  moe_mfma_kernel<<<dim3(I_ / 128, N_ / 128 + E_), blk, 0, stream>>>(
      attnb, WeT, be, lists, offs, cnt, tb, interb);
  gemm_mfma_kernel<false, 2><<<dim3(H_ / 128, N_ / 128, 2), blk, 0, stream>>>(
      interb, WoT, bo, woPart, N_, H_, I_);
  add_ln_kernel<2><<<N_, blk, 0, stream>>>(woPart, attn, g2, b2, out, (ushort*)nullptr);
}

// Round 7
// 538.298 us; speedup vs baseline: 8.7169x; 1.0141x over previous
//
#include <hip/hip_runtime.h>
#include <hip/hip_bf16.h>
#include <cstdint>

#define H_  1024
#define NH_ 16
#define DH_ 64
#define I_  4096
#define E_  8
#define B_  2
#define S_  2048
#define N_  4096        // B_*S_
#define QKVLD 3072      // fused qkv row stride
#define LN_EPS 1e-12f

typedef __attribute__((ext_vector_type(4))) float f4;
typedef __attribute__((ext_vector_type(8))) short s8v;
typedef unsigned int u32;

// ---------- helpers ----------
__device__ __forceinline__ float bf2f(unsigned short u) {
  union { unsigned int i; float f; } c; c.i = ((unsigned int)u) << 16; return c.f;
}
__device__ __forceinline__ unsigned short f2bf(float f) {
  __hip_bfloat16 h = __float2bfloat16(f);
  return *reinterpret_cast<unsigned short*>(&h);
}
__device__ __forceinline__ u32 pack_bf2(float a, float b) {
  return (u32)f2bf(a) | ((u32)f2bf(b) << 16);
}
__device__ __forceinline__ float gelu_f(float x) {
  return 0.5f * x * (1.0f + erff(x * 0.70710678118f));   // exact GELU
}
__device__ __forceinline__ void gload16(const void* g, void* l) {
  __builtin_amdgcn_global_load_lds(
      (const __attribute__((address_space(1))) void*)g,
      (__attribute__((address_space(3))) void*)l, 16, 0, 0);
}

// ---------- fp32 -> bf16 elementwise ----------
__global__ __launch_bounds__(256) void cvt_bf16_kernel(
    const float* __restrict__ in, ushort* __restrict__ out, int n8)
{
  const int t = blockIdx.x * 256 + threadIdx.x;
  if (t >= n8) return;
  const f4 x0 = *(const f4*)(in + (size_t)t * 8);
  const f4 x1 = *(const f4*)(in + (size_t)t * 8 + 4);
  s8v o;
#pragma unroll
  for (int j = 0; j < 4; ++j) { o[j] = (short)f2bf(x0[j]); o[4 + j] = (short)f2bf(x1[j]); }
  *(s8v*)(out + (size_t)t * 8) = o;
}

// ---------- fp32 [R][C] -> bf16 [C][R] transpose ----------
__global__ __launch_bounds__(256) void transpose_cvt_kernel(
    const float* __restrict__ in, ushort* __restrict__ out, int R, int C)
{
  __shared__ float tile[32][33];
  const size_t zo = (size_t)blockIdx.z * R * C;
  const int bx = blockIdx.x << 5, by = blockIdx.y << 5;
  const int tx = threadIdx.x & 31, ty = threadIdx.x >> 5;   // ty 0..7
  const float* ip = in + zo + (size_t)by * C + bx;
#pragma unroll
  for (int i = 0; i < 4; ++i)
    tile[ty + 8 * i][tx] = ip[(size_t)(ty + 8 * i) * C + tx];
  __syncthreads();
  ushort* op = out + zo + (size_t)bx * R + by;
#pragma unroll
  for (int i = 0; i < 4; ++i)
    op[(size_t)(ty + 8 * i) * R + tx] = f2bf(tile[tx][ty + 8 * i]);
}

__global__ void concat3_kernel(const float* a, const float* b, const float* c,
                               float* __restrict__ o)
{
  const int t = blockIdx.x * 256 + threadIdx.x;   // 3072 total
  if (t < 1024) o[t] = a[t];
  else if (t < 2048) o[t] = b[t - 1024];
  else o[t] = c[t - 2048];
}

// ---------- token gather: Xg[r] = X[lists[r]] (expert-sorted, coalesced) ----
__global__ __launch_bounds__(256) void gather_kernel(
    const ushort* __restrict__ X, const int* __restrict__ lists,
    ushort* __restrict__ Xg)
{
  const int r = (blockIdx.x << 1) + (threadIdx.x >> 7);
  const int c = (threadIdx.x & 127) << 3;
  const int tok = lists[r];
  *(s8v*)&Xg[(size_t)r * H_ + c] = *(const s8v*)&X[(size_t)tok * H_ + c];
}

// ---------- MFMA GEMM: C = A * W + bias, 2-phase double-buffered prefetch ----
// A [M,K] bf16 row-major, Bt = W^T [N,K] bf16 row-major. 128x128 tile, BK=32.
// KSPLIT>1: blockIdx.z covers K/KSPLIT; fp32 partials at Cout + z*M*N (bias in z0).
// BF16OUT: LDS-staged vectorized epilogue (coalesced 16B stores).
template <bool BF16OUT, int KSPLIT>
__global__ __launch_bounds__(256, 3) void gemm_mfma_kernel(
    const ushort* __restrict__ A, const ushort* __restrict__ Bt,
    const float* __restrict__ bias, void* __restrict__ Cout,
    const int M, const int N, const int K)
{
  __shared__ __align__(16) ushort Asm[2][4][128][8];
  __shared__ __align__(16) ushort Bsm[2][4][128][8];
  const int tid = threadIdx.x;
  const int w = tid >> 6, l = tid & 63;
  const int lq = l & 15, g = l >> 4;
  const int wm = w >> 1, wn = w & 1;
  const int nbx = N >> 7;
  const int nwg = nbx * (M >> 7);
  int id = blockIdx.y * nbx + blockIdx.x;
  id = (id & 7) * (nwg >> 3) + (id >> 3);     // bijective XCD swizzle
  const int m0 = (id / nbx) << 7, n0 = (id % nbx) << 7;
  const int Kspan = K / KSPLIT;
  const int kbase = (KSPLIT > 1) ? blockIdx.z * Kspan : 0;

  const ushort* a0 = A + (size_t)(m0 + l) * K + kbase + (w << 3);
  const ushort* a1 = a0 + (size_t)64 * K;
  const ushort* b0 = Bt + (size_t)(n0 + l) * K + kbase + (w << 3);
  const ushort* b1 = b0 + (size_t)64 * K;

  f4 acc[4][4] = {};
  const int nt = Kspan >> 5;
  gload16(a0, &Asm[0][w][0][0]);  gload16(a1, &Asm[0][w][64][0]);
  gload16(b0, &Bsm[0][w][0][0]);  gload16(b1, &Bsm[0][w][64][0]);
  __syncthreads();
  int cur = 0;
  for (int t = 0; t < nt; ++t) {
    if (t + 1 < nt) {
      const int kt = (t + 1) << 5;
      gload16(a0 + kt, &Asm[cur ^ 1][w][0][0]);
      gload16(a1 + kt, &Asm[cur ^ 1][w][64][0]);
      gload16(b0 + kt, &Bsm[cur ^ 1][w][0][0]);
      gload16(b1 + kt, &Bsm[cur ^ 1][w][64][0]);
    }
    s8v af[4], bfv[4];
#pragma unroll
    for (int mi = 0; mi < 4; ++mi)
      af[mi] = *(const s8v*)&Asm[cur][g][(wm << 6) + (mi << 4) + lq][0];
#pragma unroll
    for (int ni = 0; ni < 4; ++ni)
      bfv[ni] = *(const s8v*)&Bsm[cur][g][(wn << 6) + (ni << 4) + lq][0];
#pragma unroll
    for (int mi = 0; mi < 4; ++mi)
#pragma unroll
      for (int ni = 0; ni < 4; ++ni)
        acc[mi][ni] = __builtin_amdgcn_mfma_f32_16x16x32_bf16(af[mi], bfv[ni], acc[mi][ni], 0, 0, 0);
    __syncthreads();
    cur ^= 1;
  }
  if constexpr (BF16OUT) {
    // per-wave LDS scratch [16][72] overlaid on Asm (all staging reads done)
    ushort* st = (ushort*)Asm + (size_t)w * (16 * 72);
    float bs[4];
#pragma unroll
    for (int ni = 0; ni < 4; ++ni) bs[ni] = bias[n0 + (wn << 6) + (ni << 4) + lq];
#pragma unroll
    for (int mi = 0; mi < 4; ++mi) {
#pragma unroll
      for (int ni = 0; ni < 4; ++ni)
#pragma unroll
        for (int r = 0; r < 4; ++r)
          st[((g << 2) + r) * 72 + (ni << 4) + lq] = f2bf(acc[mi][ni][r] + bs[ni]);
      // lanes {l,l+16,l+32,l+48} cover 64 contiguous bytes of one row
#pragma unroll
      for (int q2 = 0; q2 < 2; ++q2) {
        const int r16 = l & 15, ch = (l >> 4) + (q2 << 2);
        const s8v vv = *(const s8v*)&st[r16 * 72 + (ch << 3)];
        *(s8v*)&((ushort*)Cout)[(size_t)(m0 + (wm << 6) + (mi << 4) + r16) * N
                                + n0 + (wn << 6) + (ch << 3)] = vv;
      }
    }
  } else {
    float* outf = (float*)Cout + (size_t)blockIdx.z * M * N;
#pragma unroll
    for (int ni = 0; ni < 4; ++ni) {
      const int col = n0 + (wn << 6) + (ni << 4) + lq;
      const float bs = (KSPLIT == 1 || blockIdx.z == 0) ? bias[col] : 0.f;
#pragma unroll
      for (int mi = 0; mi < 4; ++mi) {
        const int row = m0 + (wm << 6) + (mi << 4) + (g << 2);
#pragma unroll
        for (int r = 0; r < 4; ++r)
          outf[(size_t)(row + r) * N + col] = acc[mi][ni][r] + bs;
      }
    }
  }
}

// ---------- MoE expert GEMM (pre-gathered A, vectorized scatter epilogue) ----
__global__ __launch_bounds__(256, 3) void moe_mfma_kernel(
    const ushort* __restrict__ Xg, const ushort* __restrict__ WeT,
    const float* __restrict__ be, const int* __restrict__ lists,
    const int* __restrict__ offs, const int* __restrict__ cnt,
    const int* __restrict__ tb, ushort* __restrict__ inter)
{
  __shared__ __align__(16) ushort Asm[2][4][128][8];
  __shared__ __align__(16) ushort Bsm[2][4][128][8];
  __shared__ int tokL[128];
  const int by = blockIdx.y;
  if (by >= tb[E_]) return;
  int e = 0;
#pragma unroll
  for (int t = 1; t < E_; ++t) if (by >= tb[t]) e = t;
  const int rt = by - tb[e];
  const int base = offs[e] + (rt << 7);
  const int nrows = cnt[e] - (rt << 7);
  const int tid = threadIdx.x;
  if (tid < 128) tokL[tid] = (tid < nrows) ? lists[base + tid] : -1;
  __syncthreads();
  const int w = tid >> 6, l = tid & 63;
  const int lq = l & 15, g = l >> 4;
  const int wm = w >> 1, wn = w & 1;
  const int n0 = blockIdx.x << 7;
  const int r0 = min(base + l, N_ - 1);
  const int r1 = min(base + 64 + l, N_ - 1);
  const ushort* a0 = Xg + (size_t)r0 * H_ + (w << 3);
  const ushort* a1 = Xg + (size_t)r1 * H_ + (w << 3);
  const ushort* Wp = WeT + (size_t)e * I_ * H_;
  const ushort* b0 = Wp + (size_t)(n0 + l) * H_ + (w << 3);
  const ushort* b1 = b0 + (size_t)64 * H_;

  f4 acc[4][4] = {};
  gload16(a0, &Asm[0][w][0][0]);  gload16(a1, &Asm[0][w][64][0]);
  gload16(b0, &Bsm[0][w][0][0]);  gload16(b1, &Bsm[0][w][64][0]);
  __syncthreads();
  int cur = 0;
  for (int t = 0; t < 32; ++t) {
    if (t + 1 < 32) {
      const int kt = (t + 1) << 5;
      gload16(a0 + kt, &Asm[cur ^ 1][w][0][0]);
      gload16(a1 + kt, &Asm[cur ^ 1][w][64][0]);
      gload16(b0 + kt, &Bsm[cur ^ 1][w][0][0]);
      gload16(b1 + kt, &Bsm[cur ^ 1][w][64][0]);
    }
    s8v af[4], bfv[4];
#pragma unroll
    for (int mi = 0; mi < 4; ++mi)
      af[mi] = *(const s8v*)&Asm[cur][g][(wm << 6) + (mi << 4) + lq][0];
#pragma unroll
    for (int ni = 0; ni < 4; ++ni)
      bfv[ni] = *(const s8v*)&Bsm[cur][g][(wn << 6) + (ni << 4) + lq][0];
#pragma unroll
    for (int mi = 0; mi < 4; ++mi)
#pragma unroll
      for (int ni = 0; ni < 4; ++ni)
        acc[mi][ni] = __builtin_amdgcn_mfma_f32_16x16x32_bf16(af[mi], bfv[ni], acc[mi][ni], 0, 0, 0);
    __syncthreads();
    cur ^= 1;
  }
  // vectorized epilogue: gelu -> per-wave LDS [16][72] -> coalesced 16B stores
  {
    ushort* st = (ushort*)Asm + (size_t)w * (16 * 72);
    float bs[4];
#pragma unroll
    for (int ni = 0; ni < 4; ++ni) bs[ni] = be[(size_t)e * I_ + n0 + (wn << 6) + (ni << 4) + lq];
#pragma unroll
    for (int mi = 0; mi < 4; ++mi) {
#pragma unroll
      for (int ni = 0; ni < 4; ++ni)
#pragma unroll
        for (int r = 0; r < 4; ++r)
          st[((g << 2) + r) * 72 + (ni << 4) + lq] = f2bf(gelu_f(acc[mi][ni][r] + bs[ni]));
#pragma unroll
      for (int q2 = 0; q2 < 2; ++q2) {
        const int r16 = l & 15, ch = (l >> 4) + (q2 << 2);
        const int tok = tokL[(wm << 6) + (mi << 4) + r16];
        if (tok >= 0) {
          const s8v vv = *(const s8v*)&st[r16 * 72 + (ch << 3)];
          *(s8v*)&inter[(size_t)tok * I_ + n0 + (wn << 6) + (ch << 3)] = vv;
        }
      }
    }
  }
}

// ---------- MFMA flash attention (bf16 fused-QKV input, bf16 ctx out) ----------
__global__ __launch_bounds__(256) void attn_mfma_kernel(
    const ushort* __restrict__ qkv, ushort* __restrict__ ctx)
{
  __shared__ __align__(16) ushort Ks[64 * 72];      // [key][d]
  __shared__ __align__(16) ushort Vt[64 * 72];      // [d][key]
  __shared__ __align__(16) ushort Ps[4][16 * 72];   // per-wave P [query][key]
  const int bid0 = blockIdx.x;
  const int bid  = ((bid0 & 7) << 7) + (bid0 >> 3);   // bijective XCD swizzle
  const int bh = bid >> 5, qt = bid & 31;
  const int b = bh >> 4, h = bh & 15;
  const int tid = threadIdx.x, w = tid >> 6, l = tid & 63;
  const int lq = l & 15, g = l >> 4;
  const size_t bS = (size_t)b * S_;
  const ushort* qb = qkv + bS * QKVLD + h * DH_;
  const ushort* kb = qb + 1024;
  const ushort* vb = qb + 2048;

  s8v qf0, qf1;
  {
    const ushort* qp = qb + (size_t)(qt * 64 + w * 16 + lq) * QKVLD;
    qf0 = *(const s8v*)(qp + (g << 3));
    qf1 = *(const s8v*)(qp + 32 + (g << 3));
  }

  f4 o0 = {0,0,0,0}, o1 = {0,0,0,0}, o2 = {0,0,0,0}, o3 = {0,0,0,0};
  float mrun = -3.0e38f, lrun = 0.f;

  const int skey = tid >> 2;           // staging: key row 0..63
  const int sd   = (tid & 3) << 4;     // staging: d start {0,16,32,48}

  for (int kt = 0; kt < 32; ++kt) {
    __syncthreads();
    {
      const ushort* kp = kb + (size_t)(kt * 64 + skey) * QKVLD + sd;
      *(s8v*)&Ks[skey * 72 + sd]     = *(const s8v*)(kp);
      *(s8v*)&Ks[skey * 72 + sd + 8] = *(const s8v*)(kp + 8);
      const ushort* vp = vb + (size_t)(kt * 64 + skey) * QKVLD + sd;
      const s8v v0 = *(const s8v*)(vp);
      const s8v v1 = *(const s8v*)(vp + 8);
#pragma unroll
      for (int ii = 0; ii < 8; ++ii) {
        Vt[(sd + ii) * 72 + skey]     = v0[ii];
        Vt[(sd + 8 + ii) * 72 + skey] = v1[ii];
      }
    }
    __syncthreads();

    // QK^T (swapped): lane l holds S[key=st*16+4g+r][query=lq]
    float s[16];
#pragma unroll
    for (int st = 0; st < 4; ++st) {
      f4 acc = {0, 0, 0, 0};
      const s8v ka0 = *(const s8v*)&Ks[(st * 16 + lq) * 72 + (g << 3)];
      const s8v ka1 = *(const s8v*)&Ks[(st * 16 + lq) * 72 + 32 + (g << 3)];
      acc = __builtin_amdgcn_mfma_f32_16x16x32_bf16(ka0, qf0, acc, 0, 0, 0);
      acc = __builtin_amdgcn_mfma_f32_16x16x32_bf16(ka1, qf1, acc, 0, 0, 0);
      s[st * 4 + 0] = acc[0] * 0.125f; s[st * 4 + 1] = acc[1] * 0.125f;
      s[st * 4 + 2] = acc[2] * 0.125f; s[st * 4 + 3] = acc[3] * 0.125f;
    }

    float tmax = s[0];
#pragma unroll
    for (int i = 1; i < 16; ++i) tmax = fmaxf(tmax, s[i]);
    tmax = fmaxf(tmax, __shfl_xor(tmax, 16));
    tmax = fmaxf(tmax, __shfl_xor(tmax, 32));
    const float mnew  = fmaxf(mrun, tmax);
    const float alpha = __expf(mrun - mnew);
    float psum = 0.f;
#pragma unroll
    for (int i = 0; i < 16; ++i) { s[i] = __expf(s[i] - mnew); psum += s[i]; }
    psum += __shfl_xor(psum, 16); psum += __shfl_xor(psum, 32);
    lrun = lrun * alpha + psum; mrun = mnew;

    f4 av;
    av[0] = __shfl(alpha, g * 4 + 0); av[1] = __shfl(alpha, g * 4 + 1);
    av[2] = __shfl(alpha, g * 4 + 2); av[3] = __shfl(alpha, g * 4 + 3);
    o0 *= av; o1 *= av; o2 *= av; o3 *= av;

    {
      ushort* pw = &Ps[w][lq * 72];
#pragma unroll
      for (int st = 0; st < 4; ++st) {
        *(u32*)&pw[st * 16 + g * 4 + 0] = pack_bf2(s[st * 4 + 0], s[st * 4 + 1]);
        *(u32*)&pw[st * 16 + g * 4 + 2] = pack_bf2(s[st * 4 + 2], s[st * 4 + 3]);
      }
    }
    asm volatile("s_waitcnt lgkmcnt(0)" ::: "memory");
    __builtin_amdgcn_sched_barrier(0);

#pragma unroll
    for (int ks = 0; ks < 2; ++ks) {
      const int kof = ks * 32 + (g << 3);
      const s8v pa = *(const s8v*)&Ps[w][lq * 72 + kof];
      const s8v v0 = *(const s8v*)&Vt[( 0 + lq) * 72 + kof];
      const s8v v1 = *(const s8v*)&Vt[(16 + lq) * 72 + kof];
      const s8v v2 = *(const s8v*)&Vt[(32 + lq) * 72 + kof];
      const s8v v3 = *(const s8v*)&Vt[(48 + lq) * 72 + kof];
      o0 = __builtin_amdgcn_mfma_f32_16x16x32_bf16(pa, v0, o0, 0, 0, 0);
      o1 = __builtin_amdgcn_mfma_f32_16x16x32_bf16(pa, v1, o1, 0, 0, 0);
      o2 = __builtin_amdgcn_mfma_f32_16x16x32_bf16(pa, v2, o2, 0, 0, 0);
      o3 = __builtin_amdgcn_mfma_f32_16x16x32_bf16(pa, v3, o3, 0, 0, 0);
    }
  }

  const float inv = 1.f / lrun;
#pragma unroll
  for (int r = 0; r < 4; ++r) {
    const float li = __shfl(inv, g * 4 + r);
    ushort* op = ctx + (bS + (size_t)(qt * 64 + w * 16 + g * 4 + r)) * H_ + h * DH_ + lq;
    op[0]  = f2bf(o0[r] * li);
    op[16] = f2bf(o1[r] * li);
    op[32] = f2bf(o2[r] * li);
    op[48] = f2bf(o3[r] * li);
  }
}

// ---------- P-partial sum + residual add + LayerNorm ----------
template <int P>
__global__ __launch_bounds__(256) void add_ln_kernel(
    const float* __restrict__ a, const float* __restrict__ r,
    const float* __restrict__ g, const float* __restrict__ bta,
    float* __restrict__ out, ushort* __restrict__ ob)
{
  const int row = blockIdx.x, tid = threadIdx.x;
  const size_t base = (size_t)row * H_;
  const float4 xr = *(const float4*)(r + base + (tid << 2));
  float4 x = xr;
#pragma unroll
  for (int pp = 0; pp < P; ++pp) {
    const float4 xa = *(const float4*)(a + (size_t)pp * N_ * H_ + base + (tid << 2));
    x.x += xa.x; x.y += xa.y; x.z += xa.z; x.w += xa.w;
  }
  float s  = x.x + x.y + x.z + x.w;
  float ss = x.x * x.x + x.y * x.y + x.z * x.z + x.w * x.w;
#pragma unroll
  for (int off = 1; off < 64; off <<= 1) { s += __shfl_xor(s, off); ss += __shfl_xor(ss, off); }
  __shared__ float red[8];
  const int w = tid >> 6, ln = tid & 63;
  if (ln == 0) { red[w] = s; red[4 + w] = ss; }
  __syncthreads();
  const float S  = red[0] + red[1] + red[2] + red[3];
  const float SS = red[4] + red[5] + red[6] + red[7];
  const float mu  = S * (1.f / 1024.f);
  const float var = fmaxf(SS * (1.f / 1024.f) - mu * mu, 0.f);
  const float inv = rsqrtf(var + LN_EPS);
  const float4 gg = *(const float4*)&g[tid << 2];
  const float4 bb = *(const float4*)&bta[tid << 2];
  float4 y;
  y.x = (x.x - mu) * inv * gg.x + bb.x;
  y.y = (x.y - mu) * inv * gg.y + bb.y;
  y.z = (x.z - mu) * inv * gg.z + bb.z;
  y.w = (x.w - mu) * inv * gg.w + bb.w;
  *(float4*)&out[base + (tid << 2)] = y;
  if (ob) {
    ushort4 u;
    u.x = f2bf(y.x); u.y = f2bf(y.y); u.z = f2bf(y.z); u.w = f2bf(y.w);
    *(ushort4*)&ob[base + (tid << 2)] = u;
  }
}

// ---------- router ----------
__global__ __launch_bounds__(64) void router_kernel(
    const float* __restrict__ x, const float* __restrict__ rw,
    int* __restrict__ idx, int* __restrict__ cnt)
{
  const int t = blockIdx.x, lane = threadIdx.x;
  float acc[8] = {0.f};
  for (int c = 0; c < H_; c += 64) {
    const float xv = x[(size_t)t * H_ + c + lane];
    const float* wr = rw + (size_t)(c + lane) * E_;
    const float4 w0 = *(const float4*)wr;
    const float4 w1 = *(const float4*)(wr + 4);
    acc[0] += xv * w0.x; acc[1] += xv * w0.y; acc[2] += xv * w0.z; acc[3] += xv * w0.w;
    acc[4] += xv * w1.x; acc[5] += xv * w1.y; acc[6] += xv * w1.z; acc[7] += xv * w1.w;
  }
#pragma unroll
  for (int e = 0; e < E_; ++e) {
    float s = acc[e];
#pragma unroll
    for (int off = 1; off < 64; off <<= 1) s += __shfl_xor(s, off);
    acc[e] = s;
  }
  if (lane == 0) {
    int be_ = 0; float bv = acc[0];
#pragma unroll
    for (int e = 1; e < E_; ++e) if (acc[e] > bv) { bv = acc[e]; be_ = e; }
    idx[t] = be_;
    atomicAdd(&cnt[be_], 1);
  }
}

__global__ void init_kernel(int* cnt) { if (threadIdx.x < E_) cnt[threadIdx.x] = 0; }

__global__ void scan_kernel(const int* __restrict__ cnt, int* __restrict__ offs,
                            int* __restrict__ cursor, int* __restrict__ tb)
{
  int o = 0, tt = 0;
  for (int e = 0; e < E_; ++e) {
    offs[e] = o; cursor[e] = o; tb[e] = tt;
    o += cnt[e]; tt += (cnt[e] + 127) >> 7;
  }
  tb[E_] = tt;
}

__global__ __launch_bounds__(256) void scatter_kernel(
    const int* __restrict__ idx, int* __restrict__ cursor, int* __restrict__ lists)
{
  const int t = blockIdx.x * 256 + threadIdx.x;
  if (t < N_) {
    const int e = idx[t];
    const int p = atomicAdd(&cursor[e], 1);
    lists[p] = t;
  }
}

// ---------- launch ----------
extern "C" void kernel_launch(void* const* d_in, const int* in_sizes, int n_in,
                              void* d_out, int out_size, void* d_ws, size_t ws_size,
                              hipStream_t stream) {
  const float* x   = (const float*)d_in[0];
  const float* Wq  = (const float*)d_in[1];
  const float* bq  = (const float*)d_in[2];
  const float* Wk  = (const float*)d_in[3];
  const float* bk  = (const float*)d_in[4];
  const float* Wv  = (const float*)d_in[5];
  const float* bv  = (const float*)d_in[6];
  const float* Wao = (const float*)d_in[7];
  const float* bao = (const float*)d_in[8];
  const float* g1  = (const float*)d_in[9];
  const float* b1  = (const float*)d_in[10];
  const float* rw  = (const float*)d_in[11];
  const float* We  = (const float*)d_in[12];
  const float* be  = (const float*)d_in[13];
  const float* Wo  = (const float*)d_in[14];
  const float* bo  = (const float*)d_in[15];
  const float* g2  = (const float*)d_in[16];
  const float* b2  = (const float*)d_in[17];
  float* out = (float*)d_out;

  char* p = (char*)d_ws;
  int* idx    = (int*)p; p += (size_t)N_ * 4;
  int* cnt    = (int*)p; p += 8 * 4;
  int* offs   = (int*)p; p += 8 * 4;
  int* cursor = (int*)p; p += 8 * 4;
  int* tb     = (int*)p; p += 16 * 4;
  int* lists  = (int*)p; p += (size_t)N_ * 4;
  p = (char*)(((uintptr_t)p + 255) & ~(uintptr_t)255);
  const size_t NH = (size_t)N_ * H_;
  ushort* xb     = (ushort*)p; p += NH * 2;                 // x bf16; reused as Xg after QKV
  ushort* qkvb   = (ushort*)p;                              // fused qkv bf16 ...
  float*  woPart = (float*)p;  p += (size_t)N_ * QKVLD * 2; // ... reused: Wo fp32 partials x2
  ushort* ctxb   = (ushort*)p; p += NH * 2;                 // attn ctx bf16 (tail of woPart)
  float*  attn   = (float*)p;  p += NH * 4;                 // LN1 out fp32
  ushort* attnb  = (ushort*)p; p += NH * 2;                 // LN1 out bf16
  ushort* interb = (ushort*)p;                              // MoE inter bf16 ...
  float*  aoPart = (float*)p;  p += (size_t)N_ * I_ * 2;    // ... reused: AO fp32 partials x2
  ushort* WqkvT  = (ushort*)p; p += (size_t)QKVLD * H_ * 2; // [3072][1024]
  ushort* WaoT   = (ushort*)p; p += (size_t)H_ * H_ * 2;    // [1024][1024]
  ushort* WoT    = (ushort*)p; p += (size_t)H_ * I_ * 2;    // [1024][4096]
  ushort* WeT    = (ushort*)p; p += (size_t)E_ * I_ * H_ * 2; // [8][4096][1024]
  float*  bqkv   = (float*)p;  p += QKVLD * 4;
  ushort* Xg     = xb;                                      // expert-sorted tokens

  const dim3 blk(256);

  init_kernel<<<1, 64, 0, stream>>>(cnt);
  cvt_bf16_kernel<<<(N_ * H_ / 8 + 255) / 256, blk, 0, stream>>>(x, xb, N_ * H_ / 8);
  concat3_kernel<<<QKVLD / 256, blk, 0, stream>>>(bq, bk, bv, bqkv);
  transpose_cvt_kernel<<<dim3(32, 32, 1), blk, 0, stream>>>(Wq, WqkvT, H_, H_);
  transpose_cvt_kernel<<<dim3(32, 32, 1), blk, 0, stream>>>(Wk, WqkvT + (size_t)1024 * H_, H_, H_);
  transpose_cvt_kernel<<<dim3(32, 32, 1), blk, 0, stream>>>(Wv, WqkvT + (size_t)2048 * H_, H_, H_);
  transpose_cvt_kernel<<<dim3(32, 32, 1), blk, 0, stream>>>(Wao, WaoT, H_, H_);
  transpose_cvt_kernel<<<dim3(32, 128, 1), blk, 0, stream>>>(Wo, WoT, I_, H_);
  transpose_cvt_kernel<<<dim3(128, 32, 8), blk, 0, stream>>>(We, WeT, H_, I_);

  gemm_mfma_kernel<true, 1><<<dim3(QKVLD / 128, N_ / 128), blk, 0, stream>>>(
      xb, WqkvT, bqkv, qkvb, N_, QKVLD, H_);
  attn_mfma_kernel<<<1024, blk, 0, stream>>>(qkvb, ctxb);
  gemm_mfma_kernel<false, 2><<<dim3(H_ / 128, N_ / 128, 2), blk, 0, stream>>>(
      ctxb, WaoT, bao, aoPart, N_, H_, H_);
  add_ln_kernel<2><<<N_, blk, 0, stream>>>(aoPart, x, g1, b1, attn, attnb);
  router_kernel<<<N_, 64, 0, stream>>>(attn, rw, idx, cnt);
  scan_kernel<<<1, 1, 0, stream>>>(cnt, offs, cursor, tb);
  scatter_kernel<<<N_ / 256, blk, 0, stream>>>(idx, cursor, lists);
  gather_kernel<<<N_ / 2, blk, 0, stream>>>(attnb, lists, Xg);
  moe_mfma_kernel<<<dim3(I_ / 128, N_ / 128 + E_), blk, 0, stream>>>(
      Xg, WeT, be, lists, offs, cnt, tb, interb);
  gemm_mfma_kernel<false, 2><<<dim3(H_ / 128, N_ / 128, 2), blk, 0, stream>>>(
      interb, WoT, bo, woPart, N_, H_, I_);
  add_ln_kernel<2><<<N_, blk, 0, stream>>>(woPart, attn, g2, b2, out, (ushort*)nullptr);
}

// Round 8
// 523.386 us; speedup vs baseline: 8.9653x; 1.0285x over previous
//
#include <hip/hip_runtime.h>
#include <hip/hip_bf16.h>
#include <cstdint>

#define H_  1024
#define NH_ 16
#define DH_ 64
#define I_  4096
#define E_  8
#define B_  2
#define S_  2048
#define N_  4096        // B_*S_
#define QKVLD 3072      // fused qkv row stride
#define LN_EPS 1e-12f

typedef __attribute__((ext_vector_type(4))) float f4;
typedef __attribute__((ext_vector_type(8))) short s8v;
typedef unsigned int u32;

// ---------- helpers ----------
__device__ __forceinline__ float bf2f(unsigned short u) {
  union { unsigned int i; float f; } c; c.i = ((unsigned int)u) << 16; return c.f;
}
__device__ __forceinline__ unsigned short f2bf(float f) {
  __hip_bfloat16 h = __float2bfloat16(f);
  return *reinterpret_cast<unsigned short*>(&h);
}
__device__ __forceinline__ u32 pack_bf2(float a, float b) {
  return (u32)f2bf(a) | ((u32)f2bf(b) << 16);
}
__device__ __forceinline__ float gelu_f(float x) {
  return 0.5f * x * (1.0f + erff(x * 0.70710678118f));   // exact GELU
}
__device__ __forceinline__ void gload16(const void* g, void* l) {
  __builtin_amdgcn_global_load_lds(
      (const __attribute__((address_space(1))) void*)g,
      (__attribute__((address_space(3))) void*)l, 16, 0, 0);
}

// ---------- fp32 -> bf16 elementwise ----------
__global__ __launch_bounds__(256) void cvt_bf16_kernel(
    const float* __restrict__ in, ushort* __restrict__ out, int n8)
{
  const int t = blockIdx.x * 256 + threadIdx.x;
  if (t >= n8) return;
  const f4 x0 = *(const f4*)(in + (size_t)t * 8);
  const f4 x1 = *(const f4*)(in + (size_t)t * 8 + 4);
  s8v o;
#pragma unroll
  for (int j = 0; j < 4; ++j) { o[j] = (short)f2bf(x0[j]); o[4 + j] = (short)f2bf(x1[j]); }
  *(s8v*)(out + (size_t)t * 8) = o;
}

// ---------- fp32 [R][C] -> bf16 [C][R] transpose ----------
__global__ __launch_bounds__(256) void transpose_cvt_kernel(
    const float* __restrict__ in, ushort* __restrict__ out, int R, int C)
{
  __shared__ float tile[32][33];
  const size_t zo = (size_t)blockIdx.z * R * C;
  const int bx = blockIdx.x << 5, by = blockIdx.y << 5;
  const int tx = threadIdx.x & 31, ty = threadIdx.x >> 5;   // ty 0..7
  const float* ip = in + zo + (size_t)by * C + bx;
#pragma unroll
  for (int i = 0; i < 4; ++i)
    tile[ty + 8 * i][tx] = ip[(size_t)(ty + 8 * i) * C + tx];
  __syncthreads();
  ushort* op = out + zo + (size_t)bx * R + by;
#pragma unroll
  for (int i = 0; i < 4; ++i)
    op[(size_t)(ty + 8 * i) * R + tx] = f2bf(tile[tx][ty + 8 * i]);
}

__global__ void concat3_kernel(const float* a, const float* b, const float* c,
                               float* __restrict__ o)
{
  const int t = blockIdx.x * 256 + threadIdx.x;   // 3072 total
  if (t < 1024) o[t] = a[t];
  else if (t < 2048) o[t] = b[t - 1024];
  else o[t] = c[t - 2048];
}

// ---------- token gather: Xg[r] = X[lists[r]] (expert-sorted, coalesced) ----
__global__ __launch_bounds__(256) void gather_kernel(
    const ushort* __restrict__ X, const int* __restrict__ lists,
    ushort* __restrict__ Xg)
{
  const int r = (blockIdx.x << 1) + (threadIdx.x >> 7);
  const int c = (threadIdx.x & 127) << 3;
  const int tok = lists[r];
  *(s8v*)&Xg[(size_t)r * H_ + c] = *(const s8v*)&X[(size_t)tok * H_ + c];
}

// ---------- MFMA GEMM: C = A * W + bias, 2-deep counted-vmcnt pipeline ------
// A [M,K] bf16 row-major, Bt = W^T [N,K] bf16 row-major. 128x128 tile, BK=32.
// Loop: wait vmcnt(4) [tile t landed, t+1 in flight] -> barrier -> ds_read ->
// lgkmcnt(0) -> barrier (WAR-safe) -> issue tile t+2 -> MFMA. Never drains
// the full load queue inside the loop (T3/T4).
template <bool BF16OUT, int KSPLIT>
__global__ __launch_bounds__(256, 4) void gemm_mfma_kernel(
    const ushort* __restrict__ A, const ushort* __restrict__ Bt,
    const float* __restrict__ bias, void* __restrict__ Cout,
    const int M, const int N, const int K)
{
  __shared__ __align__(16) ushort Asm[2][4][128][8];
  __shared__ __align__(16) ushort Bsm[2][4][128][8];
  const int tid = threadIdx.x;
  const int w = tid >> 6, l = tid & 63;
  const int lq = l & 15, g = l >> 4;
  const int wm = w >> 1, wn = w & 1;
  const int nbx = N >> 7;
  const int nwg = nbx * (M >> 7);
  int id = blockIdx.y * nbx + blockIdx.x;
  id = (id & 7) * (nwg >> 3) + (id >> 3);     // bijective XCD swizzle
  const int m0 = (id / nbx) << 7, n0 = (id % nbx) << 7;
  const int Kspan = K / KSPLIT;
  const int kbase = (KSPLIT > 1) ? blockIdx.z * Kspan : 0;

  const ushort* a0 = A + (size_t)(m0 + l) * K + kbase + (w << 3);
  const ushort* a1 = a0 + (size_t)64 * K;
  const ushort* b0 = Bt + (size_t)(n0 + l) * K + kbase + (w << 3);
  const ushort* b1 = b0 + (size_t)64 * K;

  f4 acc[4][4] = {};
  const int nt = Kspan >> 5;
#define STAGE_G(tt, buf)                                   \
  { const int kt_ = (tt) << 5;                             \
    gload16(a0 + kt_, &Asm[buf][w][0][0]);                 \
    gload16(a1 + kt_, &Asm[buf][w][64][0]);                \
    gload16(b0 + kt_, &Bsm[buf][w][0][0]);                 \
    gload16(b1 + kt_, &Bsm[buf][w][64][0]); }
  STAGE_G(0, 0);
  STAGE_G(1, 1);
  for (int t = 0; t < nt; ++t) {
    const int cur = t & 1;
    if (t + 1 < nt) { asm volatile("s_waitcnt vmcnt(4)" ::: "memory"); }
    else            { asm volatile("s_waitcnt vmcnt(0)" ::: "memory"); }
    __builtin_amdgcn_s_barrier();
    __builtin_amdgcn_sched_barrier(0);
    s8v af[4], bfv[4];
#pragma unroll
    for (int mi = 0; mi < 4; ++mi)
      af[mi] = *(const s8v*)&Asm[cur][g][(wm << 6) + (mi << 4) + lq][0];
#pragma unroll
    for (int ni = 0; ni < 4; ++ni)
      bfv[ni] = *(const s8v*)&Bsm[cur][g][(wn << 6) + (ni << 4) + lq][0];
    asm volatile("s_waitcnt lgkmcnt(0)" ::: "memory");
    __builtin_amdgcn_sched_barrier(0);
    __builtin_amdgcn_s_barrier();
    __builtin_amdgcn_sched_barrier(0);
    if (t + 2 < nt) STAGE_G(t + 2, cur);
#pragma unroll
    for (int mi = 0; mi < 4; ++mi)
#pragma unroll
      for (int ni = 0; ni < 4; ++ni)
        acc[mi][ni] = __builtin_amdgcn_mfma_f32_16x16x32_bf16(af[mi], bfv[ni], acc[mi][ni], 0, 0, 0);
  }
#undef STAGE_G
  if constexpr (BF16OUT) {
    // per-wave LDS scratch [16][72] overlaid on Asm (all staging reads done)
    ushort* st = (ushort*)Asm + (size_t)w * (16 * 72);
    float bs[4];
#pragma unroll
    for (int ni = 0; ni < 4; ++ni) bs[ni] = bias[n0 + (wn << 6) + (ni << 4) + lq];
#pragma unroll
    for (int mi = 0; mi < 4; ++mi) {
#pragma unroll
      for (int ni = 0; ni < 4; ++ni)
#pragma unroll
        for (int r = 0; r < 4; ++r)
          st[((g << 2) + r) * 72 + (ni << 4) + lq] = f2bf(acc[mi][ni][r] + bs[ni]);
#pragma unroll
      for (int q2 = 0; q2 < 2; ++q2) {
        const int r16 = l & 15, ch = (l >> 4) + (q2 << 2);
        const s8v vv = *(const s8v*)&st[r16 * 72 + (ch << 3)];
        *(s8v*)&((ushort*)Cout)[(size_t)(m0 + (wm << 6) + (mi << 4) + r16) * N
                                + n0 + (wn << 6) + (ch << 3)] = vv;
      }
    }
  } else {
    float* outf = (float*)Cout + (size_t)blockIdx.z * M * N;
#pragma unroll
    for (int ni = 0; ni < 4; ++ni) {
      const int col = n0 + (wn << 6) + (ni << 4) + lq;
      const float bs = (KSPLIT == 1 || blockIdx.z == 0) ? bias[col] : 0.f;
#pragma unroll
      for (int mi = 0; mi < 4; ++mi) {
        const int row = m0 + (wm << 6) + (mi << 4) + (g << 2);
#pragma unroll
        for (int r = 0; r < 4; ++r)
          outf[(size_t)(row + r) * N + col] = acc[mi][ni][r] + bs;
      }
    }
  }
}

// ---------- MoE expert GEMM (pre-gathered A, counted-vmcnt pipeline) --------
__global__ __launch_bounds__(256, 4) void moe_mfma_kernel(
    const ushort* __restrict__ Xg, const ushort* __restrict__ WeT,
    const float* __restrict__ be, const int* __restrict__ lists,
    const int* __restrict__ offs, const int* __restrict__ cnt,
    const int* __restrict__ tb, ushort* __restrict__ inter)
{
  __shared__ __align__(16) ushort Asm[2][4][128][8];
  __shared__ __align__(16) ushort Bsm[2][4][128][8];
  __shared__ int tokL[128];
  const int by = blockIdx.y;
  if (by >= tb[E_]) return;
  int e = 0;
#pragma unroll
  for (int t = 1; t < E_; ++t) if (by >= tb[t]) e = t;
  const int rt = by - tb[e];
  const int base = offs[e] + (rt << 7);
  const int nrows = cnt[e] - (rt << 7);
  const int tid = threadIdx.x;
  if (tid < 128) tokL[tid] = (tid < nrows) ? lists[base + tid] : -1;
  __syncthreads();           // tokL visible; also drains vmcnt to 0
  const int w = tid >> 6, l = tid & 63;
  const int lq = l & 15, g = l >> 4;
  const int wm = w >> 1, wn = w & 1;
  const int n0 = blockIdx.x << 7;
  const int r0 = min(base + l, N_ - 1);
  const int r1 = min(base + 64 + l, N_ - 1);
  const ushort* a0 = Xg + (size_t)r0 * H_ + (w << 3);
  const ushort* a1 = Xg + (size_t)r1 * H_ + (w << 3);
  const ushort* Wp = WeT + (size_t)e * I_ * H_;
  const ushort* b0 = Wp + (size_t)(n0 + l) * H_ + (w << 3);
  const ushort* b1 = b0 + (size_t)64 * H_;

  f4 acc[4][4] = {};
#define STAGE_M(tt, buf)                                   \
  { const int kt_ = (tt) << 5;                             \
    gload16(a0 + kt_, &Asm[buf][w][0][0]);                 \
    gload16(a1 + kt_, &Asm[buf][w][64][0]);                \
    gload16(b0 + kt_, &Bsm[buf][w][0][0]);                 \
    gload16(b1 + kt_, &Bsm[buf][w][64][0]); }
  STAGE_M(0, 0);
  STAGE_M(1, 1);
  for (int t = 0; t < 32; ++t) {
    const int cur = t & 1;
    if (t + 1 < 32) { asm volatile("s_waitcnt vmcnt(4)" ::: "memory"); }
    else            { asm volatile("s_waitcnt vmcnt(0)" ::: "memory"); }
    __builtin_amdgcn_s_barrier();
    __builtin_amdgcn_sched_barrier(0);
    s8v af[4], bfv[4];
#pragma unroll
    for (int mi = 0; mi < 4; ++mi)
      af[mi] = *(const s8v*)&Asm[cur][g][(wm << 6) + (mi << 4) + lq][0];
#pragma unroll
    for (int ni = 0; ni < 4; ++ni)
      bfv[ni] = *(const s8v*)&Bsm[cur][g][(wn << 6) + (ni << 4) + lq][0];
    asm volatile("s_waitcnt lgkmcnt(0)" ::: "memory");
    __builtin_amdgcn_sched_barrier(0);
    __builtin_amdgcn_s_barrier();
    __builtin_amdgcn_sched_barrier(0);
    if (t + 2 < 32) STAGE_M(t + 2, cur);
#pragma unroll
    for (int mi = 0; mi < 4; ++mi)
#pragma unroll
      for (int ni = 0; ni < 4; ++ni)
        acc[mi][ni] = __builtin_amdgcn_mfma_f32_16x16x32_bf16(af[mi], bfv[ni], acc[mi][ni], 0, 0, 0);
  }
#undef STAGE_M
  // vectorized epilogue: gelu -> per-wave LDS [16][72] -> coalesced 16B stores
  {
    ushort* st = (ushort*)Asm + (size_t)w * (16 * 72);
    float bs[4];
#pragma unroll
    for (int ni = 0; ni < 4; ++ni) bs[ni] = be[(size_t)e * I_ + n0 + (wn << 6) + (ni << 4) + lq];
#pragma unroll
    for (int mi = 0; mi < 4; ++mi) {
#pragma unroll
      for (int ni = 0; ni < 4; ++ni)
#pragma unroll
        for (int r = 0; r < 4; ++r)
          st[((g << 2) + r) * 72 + (ni << 4) + lq] = f2bf(gelu_f(acc[mi][ni][r] + bs[ni]));
#pragma unroll
      for (int q2 = 0; q2 < 2; ++q2) {
        const int r16 = l & 15, ch = (l >> 4) + (q2 << 2);
        const int tok = tokL[(wm << 6) + (mi << 4) + r16];
        if (tok >= 0) {
          const s8v vv = *(const s8v*)&st[r16 * 72 + (ch << 3)];
          *(s8v*)&inter[(size_t)tok * I_ + n0 + (wn << 6) + (ch << 3)] = vv;
        }
      }
    }
  }
}

// ---------- MFMA flash attention (bf16 fused-QKV input, bf16 ctx out) ----------
__global__ __launch_bounds__(256) void attn_mfma_kernel(
    const ushort* __restrict__ qkv, ushort* __restrict__ ctx)
{
  __shared__ __align__(16) ushort Ks[64 * 72];      // [key][d]
  __shared__ __align__(16) ushort Vt[64 * 72];      // [d][key]
  __shared__ __align__(16) ushort Ps[4][16 * 72];   // per-wave P [query][key]
  const int bid0 = blockIdx.x;
  const int bid  = ((bid0 & 7) << 7) + (bid0 >> 3);   // bijective XCD swizzle
  const int bh = bid >> 5, qt = bid & 31;
  const int b = bh >> 4, h = bh & 15;
  const int tid = threadIdx.x, w = tid >> 6, l = tid & 63;
  const int lq = l & 15, g = l >> 4;
  const size_t bS = (size_t)b * S_;
  const ushort* qb = qkv + bS * QKVLD + h * DH_;
  const ushort* kb = qb + 1024;
  const ushort* vb = qb + 2048;

  s8v qf0, qf1;
  {
    const ushort* qp = qb + (size_t)(qt * 64 + w * 16 + lq) * QKVLD;
    qf0 = *(const s8v*)(qp + (g << 3));
    qf1 = *(const s8v*)(qp + 32 + (g << 3));
  }

  f4 o0 = {0,0,0,0}, o1 = {0,0,0,0}, o2 = {0,0,0,0}, o3 = {0,0,0,0};
  float mrun = -3.0e38f, lrun = 0.f;

  const int skey = tid >> 2;           // staging: key row 0..63
  const int sd   = (tid & 3) << 4;     // staging: d start {0,16,32,48}

  for (int kt = 0; kt < 32; ++kt) {
    __syncthreads();
    {
      const ushort* kp = kb + (size_t)(kt * 64 + skey) * QKVLD + sd;
      *(s8v*)&Ks[skey * 72 + sd]     = *(const s8v*)(kp);
      *(s8v*)&Ks[skey * 72 + sd + 8] = *(const s8v*)(kp + 8);
      const ushort* vp = vb + (size_t)(kt * 64 + skey) * QKVLD + sd;
      const s8v v0 = *(const s8v*)(vp);
      const s8v v1 = *(const s8v*)(vp + 8);
#pragma unroll
      for (int ii = 0; ii < 8; ++ii) {
        Vt[(sd + ii) * 72 + skey]     = v0[ii];
        Vt[(sd + 8 + ii) * 72 + skey] = v1[ii];
      }
    }
    __syncthreads();

    // QK^T (swapped): lane l holds S[key=st*16+4g+r][query=lq]
    float s[16];
#pragma unroll
    for (int st = 0; st < 4; ++st) {
      f4 acc = {0, 0, 0, 0};
      const s8v ka0 = *(const s8v*)&Ks[(st * 16 + lq) * 72 + (g << 3)];
      const s8v ka1 = *(const s8v*)&Ks[(st * 16 + lq) * 72 + 32 + (g << 3)];
      acc = __builtin_amdgcn_mfma_f32_16x16x32_bf16(ka0, qf0, acc, 0, 0, 0);
      acc = __builtin_amdgcn_mfma_f32_16x16x32_bf16(ka1, qf1, acc, 0, 0, 0);
      s[st * 4 + 0] = acc[0] * 0.125f; s[st * 4 + 1] = acc[1] * 0.125f;
      s[st * 4 + 2] = acc[2] * 0.125f; s[st * 4 + 3] = acc[3] * 0.125f;
    }

    float tmax = s[0];
#pragma unroll
    for (int i = 1; i < 16; ++i) tmax = fmaxf(tmax, s[i]);
    tmax = fmaxf(tmax, __shfl_xor(tmax, 16));
    tmax = fmaxf(tmax, __shfl_xor(tmax, 32));
    const float mnew  = fmaxf(mrun, tmax);
    const float alpha = __expf(mrun - mnew);
    float psum = 0.f;
#pragma unroll
    for (int i = 0; i < 16; ++i) { s[i] = __expf(s[i] - mnew); psum += s[i]; }
    psum += __shfl_xor(psum, 16); psum += __shfl_xor(psum, 32);
    lrun = lrun * alpha + psum; mrun = mnew;

    f4 av;
    av[0] = __shfl(alpha, g * 4 + 0); av[1] = __shfl(alpha, g * 4 + 1);
    av[2] = __shfl(alpha, g * 4 + 2); av[3] = __shfl(alpha, g * 4 + 3);
    o0 *= av; o1 *= av; o2 *= av; o3 *= av;

    {
      ushort* pw = &Ps[w][lq * 72];
#pragma unroll
      for (int st = 0; st < 4; ++st) {
        *(u32*)&pw[st * 16 + g * 4 + 0] = pack_bf2(s[st * 4 + 0], s[st * 4 + 1]);
        *(u32*)&pw[st * 16 + g * 4 + 2] = pack_bf2(s[st * 4 + 2], s[st * 4 + 3]);
      }
    }
    asm volatile("s_waitcnt lgkmcnt(0)" ::: "memory");
    __builtin_amdgcn_sched_barrier(0);

#pragma unroll
    for (int ks = 0; ks < 2; ++ks) {
      const int kof = ks * 32 + (g << 3);
      const s8v pa = *(const s8v*)&Ps[w][lq * 72 + kof];
      const s8v v0 = *(const s8v*)&Vt[( 0 + lq) * 72 + kof];
      const s8v v1 = *(const s8v*)&Vt[(16 + lq) * 72 + kof];
      const s8v v2 = *(const s8v*)&Vt[(32 + lq) * 72 + kof];
      const s8v v3 = *(const s8v*)&Vt[(48 + lq) * 72 + kof];
      o0 = __builtin_amdgcn_mfma_f32_16x16x32_bf16(pa, v0, o0, 0, 0, 0);
      o1 = __builtin_amdgcn_mfma_f32_16x16x32_bf16(pa, v1, o1, 0, 0, 0);
      o2 = __builtin_amdgcn_mfma_f32_16x16x32_bf16(pa, v2, o2, 0, 0, 0);
      o3 = __builtin_amdgcn_mfma_f32_16x16x32_bf16(pa, v3, o3, 0, 0, 0);
    }
  }

  const float inv = 1.f / lrun;
#pragma unroll
  for (int r = 0; r < 4; ++r) {
    const float li = __shfl(inv, g * 4 + r);
    ushort* op = ctx + (bS + (size_t)(qt * 64 + w * 16 + g * 4 + r)) * H_ + h * DH_ + lq;
    op[0]  = f2bf(o0[r] * li);
    op[16] = f2bf(o1[r] * li);
    op[32] = f2bf(o2[r] * li);
    op[48] = f2bf(o3[r] * li);
  }
}

// ---------- P-partial sum + residual add + LayerNorm ----------
template <int P>
__global__ __launch_bounds__(256) void add_ln_kernel(
    const float* __restrict__ a, const float* __restrict__ r,
    const float* __restrict__ g, const float* __restrict__ bta,
    float* __restrict__ out, ushort* __restrict__ ob)
{
  const int row = blockIdx.x, tid = threadIdx.x;
  const size_t base = (size_t)row * H_;
  const float4 xr = *(const float4*)(r + base + (tid << 2));
  float4 x = xr;
#pragma unroll
  for (int pp = 0; pp < P; ++pp) {
    const float4 xa = *(const float4*)(a + (size_t)pp * N_ * H_ + base + (tid << 2));
    x.x += xa.x; x.y += xa.y; x.z += xa.z; x.w += xa.w;
  }
  float s  = x.x + x.y + x.z + x.w;
  float ss = x.x * x.x + x.y * x.y + x.z * x.z + x.w * x.w;
#pragma unroll
  for (int off = 1; off < 64; off <<= 1) { s += __shfl_xor(s, off); ss += __shfl_xor(ss, off); }
  __shared__ float red[8];
  const int w = tid >> 6, ln = tid & 63;
  if (ln == 0) { red[w] = s; red[4 + w] = ss; }
  __syncthreads();
  const float S  = red[0] + red[1] + red[2] + red[3];
  const float SS = red[4] + red[5] + red[6] + red[7];
  const float mu  = S * (1.f / 1024.f);
  const float var = fmaxf(SS * (1.f / 1024.f) - mu * mu, 0.f);
  const float inv = rsqrtf(var + LN_EPS);
  const float4 gg = *(const float4*)&g[tid << 2];
  const float4 bb = *(const float4*)&bta[tid << 2];
  float4 y;
  y.x = (x.x - mu) * inv * gg.x + bb.x;
  y.y = (x.y - mu) * inv * gg.y + bb.y;
  y.z = (x.z - mu) * inv * gg.z + bb.z;
  y.w = (x.w - mu) * inv * gg.w + bb.w;
  *(float4*)&out[base + (tid << 2)] = y;
  if (ob) {
    ushort4 u;
    u.x = f2bf(y.x); u.y = f2bf(y.y); u.z = f2bf(y.z); u.w = f2bf(y.w);
    *(ushort4*)&ob[base + (tid << 2)] = u;
  }
}

// ---------- router ----------
__global__ __launch_bounds__(64) void router_kernel(
    const float* __restrict__ x, const float* __restrict__ rw,
    int* __restrict__ idx, int* __restrict__ cnt)
{
  const int t = blockIdx.x, lane = threadIdx.x;
  float acc[8] = {0.f};
  for (int c = 0; c < H_; c += 64) {
    const float xv = x[(size_t)t * H_ + c + lane];
    const float* wr = rw + (size_t)(c + lane) * E_;
    const float4 w0 = *(const float4*)wr;
    const float4 w1 = *(const float4*)(wr + 4);
    acc[0] += xv * w0.x; acc[1] += xv * w0.y; acc[2] += xv * w0.z; acc[3] += xv * w0.w;
    acc[4] += xv * w1.x; acc[5] += xv * w1.y; acc[6] += xv * w1.z; acc[7] += xv * w1.w;
  }
#pragma unroll
  for (int e = 0; e < E_; ++e) {
    float s = acc[e];
#pragma unroll
    for (int off = 1; off < 64; off <<= 1) s += __shfl_xor(s, off);
    acc[e] = s;
  }
  if (lane == 0) {
    int be_ = 0; float bv = acc[0];
#pragma unroll
    for (int e = 1; e < E_; ++e) if (acc[e] > bv) { bv = acc[e]; be_ = e; }
    idx[t] = be_;
    atomicAdd(&cnt[be_], 1);
  }
}

__global__ void init_kernel(int* cnt) { if (threadIdx.x < E_) cnt[threadIdx.x] = 0; }

__global__ void scan_kernel(const int* __restrict__ cnt, int* __restrict__ offs,
                            int* __restrict__ cursor, int* __restrict__ tb)
{
  int o = 0, tt = 0;
  for (int e = 0; e < E_; ++e) {
    offs[e] = o; cursor[e] = o; tb[e] = tt;
    o += cnt[e]; tt += (cnt[e] + 127) >> 7;
  }
  tb[E_] = tt;
}

__global__ __launch_bounds__(256) void scatter_kernel(
    const int* __restrict__ idx, int* __restrict__ cursor, int* __restrict__ lists)
{
  const int t = blockIdx.x * 256 + threadIdx.x;
  if (t < N_) {
    const int e = idx[t];
    const int p = atomicAdd(&cursor[e], 1);
    lists[p] = t;
  }
}

// ---------- launch ----------
extern "C" void kernel_launch(void* const* d_in, const int* in_sizes, int n_in,
                              void* d_out, int out_size, void* d_ws, size_t ws_size,
                              hipStream_t stream) {
  const float* x   = (const float*)d_in[0];
  const float* Wq  = (const float*)d_in[1];
  const float* bq  = (const float*)d_in[2];
  const float* Wk  = (const float*)d_in[3];
  const float* bk  = (const float*)d_in[4];
  const float* Wv  = (const float*)d_in[5];
  const float* bv  = (const float*)d_in[6];
  const float* Wao = (const float*)d_in[7];
  const float* bao = (const float*)d_in[8];
  const float* g1  = (const float*)d_in[9];
  const float* b1  = (const float*)d_in[10];
  const float* rw  = (const float*)d_in[11];
  const float* We  = (const float*)d_in[12];
  const float* be  = (const float*)d_in[13];
  const float* Wo  = (const float*)d_in[14];
  const float* bo  = (const float*)d_in[15];
  const float* g2  = (const float*)d_in[16];
  const float* b2  = (const float*)d_in[17];
  float* out = (float*)d_out;

  char* p = (char*)d_ws;
  int* idx    = (int*)p; p += (size_t)N_ * 4;
  int* cnt    = (int*)p; p += 8 * 4;
  int* offs   = (int*)p; p += 8 * 4;
  int* cursor = (int*)p; p += 8 * 4;
  int* tb     = (int*)p; p += 16 * 4;
  int* lists  = (int*)p; p += (size_t)N_ * 4;
  p = (char*)(((uintptr_t)p + 255) & ~(uintptr_t)255);
  const size_t NH = (size_t)N_ * H_;
  ushort* xb     = (ushort*)p; p += NH * 2;                 // x bf16; reused as Xg after QKV
  ushort* qkvb   = (ushort*)p;                              // fused qkv bf16 ...
  float*  woPart = (float*)p;  p += (size_t)N_ * QKVLD * 2; // ... reused: Wo fp32 partials x2
  ushort* ctxb   = (ushort*)p; p += NH * 2;                 // attn ctx bf16 (tail of woPart)
  float*  attn   = (float*)p;  p += NH * 4;                 // LN1 out fp32
  ushort* attnb  = (ushort*)p; p += NH * 2;                 // LN1 out bf16
  ushort* interb = (ushort*)p;                              // MoE inter bf16 ...
  float*  aoPart = (float*)p;  p += (size_t)N_ * I_ * 2;    // ... reused: AO fp32 partials x2
  ushort* WqkvT  = (ushort*)p; p += (size_t)QKVLD * H_ * 2; // [3072][1024]
  ushort* WaoT   = (ushort*)p; p += (size_t)H_ * H_ * 2;    // [1024][1024]
  ushort* WoT    = (ushort*)p; p += (size_t)H_ * I_ * 2;    // [1024][4096]
  ushort* WeT    = (ushort*)p; p += (size_t)E_ * I_ * H_ * 2; // [8][4096][1024]
  float*  bqkv   = (float*)p;  p += QKVLD * 4;
  ushort* Xg     = xb;                                      // expert-sorted tokens

  const dim3 blk(256);

  init_kernel<<<1, 64, 0, stream>>>(cnt);
  cvt_bf16_kernel<<<(N_ * H_ / 8 + 255) / 256, blk, 0, stream>>>(x, xb, N_ * H_ / 8);
  concat3_kernel<<<QKVLD / 256, blk, 0, stream>>>(bq, bk, bv, bqkv);
  transpose_cvt_kernel<<<dim3(32, 32, 1), blk, 0, stream>>>(Wq, WqkvT, H_, H_);
  transpose_cvt_kernel<<<dim3(32, 32, 1), blk, 0, stream>>>(Wk, WqkvT + (size_t)1024 * H_, H_, H_);
  transpose_cvt_kernel<<<dim3(32, 32, 1), blk, 0, stream>>>(Wv, WqkvT + (size_t)2048 * H_, H_, H_);
  transpose_cvt_kernel<<<dim3(32, 32, 1), blk, 0, stream>>>(Wao, WaoT, H_, H_);
  transpose_cvt_kernel<<<dim3(32, 128, 1), blk, 0, stream>>>(Wo, WoT, I_, H_);
  transpose_cvt_kernel<<<dim3(128, 32, 8), blk, 0, stream>>>(We, WeT, H_, I_);

  gemm_mfma_kernel<true, 1><<<dim3(QKVLD / 128, N_ / 128), blk, 0, stream>>>(
      xb, WqkvT, bqkv, qkvb, N_, QKVLD, H_);
  attn_mfma_kernel<<<1024, blk, 0, stream>>>(qkvb, ctxb);
  gemm_mfma_kernel<false, 2><<<dim3(H_ / 128, N_ / 128, 2), blk, 0, stream>>>(
      ctxb, WaoT, bao, aoPart, N_, H_, H_);
  add_ln_kernel<2><<<N_, blk, 0, stream>>>(aoPart, x, g1, b1, attn, attnb);
  router_kernel<<<N_, 64, 0, stream>>>(attn, rw, idx, cnt);
  scan_kernel<<<1, 1, 0, stream>>>(cnt, offs, cursor, tb);
  scatter_kernel<<<N_ / 256, blk, 0, stream>>>(idx, cursor, lists);
  gather_kernel<<<N_ / 2, blk, 0, stream>>>(attnb, lists, Xg);
  moe_mfma_kernel<<<dim3(I_ / 128, N_ / 128 + E_), blk, 0, stream>>>(
      Xg, WeT, be, lists, offs, cnt, tb, interb);
  gemm_mfma_kernel<false, 2><<<dim3(H_ / 128, N_ / 128, 2), blk, 0, stream>>>(
      interb, WoT, bo, woPart, N_, H_, I_);
  add_ln_kernel<2><<<N_, blk, 0, stream>>>(woPart, attn, g2, b2, out, (ushort*)nullptr);
}

// Round 9
// 506.081 us; speedup vs baseline: 9.2718x; 1.0342x over previous
//
#include <hip/hip_runtime.h>
#include <hip/hip_bf16.h>
#include <cstdint>

#define H_  1024
#define NH_ 16
#define DH_ 64
#define I_  4096
#define E_  8
#define B_  2
#define S_  2048
#define N_  4096        // B_*S_
#define QKVLD 3072      // fused qkv row stride
#define LN_EPS 1e-12f

typedef __attribute__((ext_vector_type(4))) float f4;
typedef __attribute__((ext_vector_type(8))) short s8v;
typedef unsigned int u32;

// ---------- helpers ----------
__device__ __forceinline__ float bf2f(unsigned short u) {
  union { unsigned int i; float f; } c; c.i = ((unsigned int)u) << 16; return c.f;
}
__device__ __forceinline__ unsigned short f2bf(float f) {
  __hip_bfloat16 h = __float2bfloat16(f);
  return *reinterpret_cast<unsigned short*>(&h);
}
__device__ __forceinline__ u32 pack_bf2(float a, float b) {
  return (u32)f2bf(a) | ((u32)f2bf(b) << 16);
}
__device__ __forceinline__ float gelu_f(float x) {
  return 0.5f * x * (1.0f + erff(x * 0.70710678118f));   // exact GELU
}
__device__ __forceinline__ void gload16(const void* g, void* l) {
  __builtin_amdgcn_global_load_lds(
      (const __attribute__((address_space(1))) void*)g,
      (__attribute__((address_space(3))) void*)l, 16, 0, 0);
}

// ---------- fp32 -> bf16 elementwise ----------
__global__ __launch_bounds__(256) void cvt_bf16_kernel(
    const float* __restrict__ in, ushort* __restrict__ out, int n8)
{
  const int t = blockIdx.x * 256 + threadIdx.x;
  if (t >= n8) return;
  const f4 x0 = *(const f4*)(in + (size_t)t * 8);
  const f4 x1 = *(const f4*)(in + (size_t)t * 8 + 4);
  s8v o;
#pragma unroll
  for (int j = 0; j < 4; ++j) { o[j] = (short)f2bf(x0[j]); o[4 + j] = (short)f2bf(x1[j]); }
  *(s8v*)(out + (size_t)t * 8) = o;
}

// ---------- fp32 [R][C] -> bf16 [C][R] transpose ----------
__global__ __launch_bounds__(256) void transpose_cvt_kernel(
    const float* __restrict__ in, ushort* __restrict__ out, int R, int C)
{
  __shared__ float tile[32][33];
  const size_t zo = (size_t)blockIdx.z * R * C;
  const int bx = blockIdx.x << 5, by = blockIdx.y << 5;
  const int tx = threadIdx.x & 31, ty = threadIdx.x >> 5;   // ty 0..7
  const float* ip = in + zo + (size_t)by * C + bx;
#pragma unroll
  for (int i = 0; i < 4; ++i)
    tile[ty + 8 * i][tx] = ip[(size_t)(ty + 8 * i) * C + tx];
  __syncthreads();
  ushort* op = out + zo + (size_t)bx * R + by;
#pragma unroll
  for (int i = 0; i < 4; ++i)
    op[(size_t)(ty + 8 * i) * R + tx] = f2bf(tile[tx][ty + 8 * i]);
}

__global__ void concat3_kernel(const float* a, const float* b, const float* c,
                               float* __restrict__ o)
{
  const int t = blockIdx.x * 256 + threadIdx.x;   // 3072 total
  if (t < 1024) o[t] = a[t];
  else if (t < 2048) o[t] = b[t - 1024];
  else o[t] = c[t - 2048];
}

// ---------- token gather: Xg[r] = X[lists[r]] (expert-sorted, coalesced) ----
__global__ __launch_bounds__(256) void gather_kernel(
    const ushort* __restrict__ X, const int* __restrict__ lists,
    ushort* __restrict__ Xg)
{
  const int r = (blockIdx.x << 1) + (threadIdx.x >> 7);
  const int c = (threadIdx.x & 127) << 3;
  const int tok = lists[r];
  *(s8v*)&Xg[(size_t)r * H_ + c] = *(const s8v*)&X[(size_t)tok * H_ + c];
}

// ---------- MFMA GEMM: C = A * W + bias, 2-deep counted-vmcnt pipeline ------
template <bool BF16OUT, int KSPLIT>
__global__ __launch_bounds__(256, 4) void gemm_mfma_kernel(
    const ushort* __restrict__ A, const ushort* __restrict__ Bt,
    const float* __restrict__ bias, void* __restrict__ Cout,
    const int M, const int N, const int K)
{
  __shared__ __align__(16) ushort Asm[2][4][128][8];
  __shared__ __align__(16) ushort Bsm[2][4][128][8];
  const int tid = threadIdx.x;
  const int w = tid >> 6, l = tid & 63;
  const int lq = l & 15, g = l >> 4;
  const int wm = w >> 1, wn = w & 1;
  const int nbx = N >> 7;
  const int nwg = nbx * (M >> 7);
  int id = blockIdx.y * nbx + blockIdx.x;
  id = (id & 7) * (nwg >> 3) + (id >> 3);     // bijective XCD swizzle
  const int m0 = (id / nbx) << 7, n0 = (id % nbx) << 7;
  const int Kspan = K / KSPLIT;
  const int kbase = (KSPLIT > 1) ? blockIdx.z * Kspan : 0;

  const ushort* a0 = A + (size_t)(m0 + l) * K + kbase + (w << 3);
  const ushort* a1 = a0 + (size_t)64 * K;
  const ushort* b0 = Bt + (size_t)(n0 + l) * K + kbase + (w << 3);
  const ushort* b1 = b0 + (size_t)64 * K;

  f4 acc[4][4] = {};
  const int nt = Kspan >> 5;
#define STAGE_G(tt, buf)                                   \
  { const int kt_ = (tt) << 5;                             \
    gload16(a0 + kt_, &Asm[buf][w][0][0]);                 \
    gload16(a1 + kt_, &Asm[buf][w][64][0]);                \
    gload16(b0 + kt_, &Bsm[buf][w][0][0]);                 \
    gload16(b1 + kt_, &Bsm[buf][w][64][0]); }
  STAGE_G(0, 0);
  STAGE_G(1, 1);
  for (int t = 0; t < nt; ++t) {
    const int cur = t & 1;
    if (t + 1 < nt) { asm volatile("s_waitcnt vmcnt(4)" ::: "memory"); }
    else            { asm volatile("s_waitcnt vmcnt(0)" ::: "memory"); }
    __builtin_amdgcn_s_barrier();
    __builtin_amdgcn_sched_barrier(0);
    s8v af[4], bfv[4];
#pragma unroll
    for (int mi = 0; mi < 4; ++mi)
      af[mi] = *(const s8v*)&Asm[cur][g][(wm << 6) + (mi << 4) + lq][0];
#pragma unroll
    for (int ni = 0; ni < 4; ++ni)
      bfv[ni] = *(const s8v*)&Bsm[cur][g][(wn << 6) + (ni << 4) + lq][0];
    asm volatile("s_waitcnt lgkmcnt(0)" ::: "memory");
    __builtin_amdgcn_sched_barrier(0);
    __builtin_amdgcn_s_barrier();
    __builtin_amdgcn_sched_barrier(0);
    if (t + 2 < nt) STAGE_G(t + 2, cur);
#pragma unroll
    for (int mi = 0; mi < 4; ++mi)
#pragma unroll
      for (int ni = 0; ni < 4; ++ni)
        acc[mi][ni] = __builtin_amdgcn_mfma_f32_16x16x32_bf16(af[mi], bfv[ni], acc[mi][ni], 0, 0, 0);
  }
#undef STAGE_G
  if constexpr (BF16OUT) {
    ushort* st = (ushort*)Asm + (size_t)w * (16 * 72);
    float bs[4];
#pragma unroll
    for (int ni = 0; ni < 4; ++ni) bs[ni] = bias[n0 + (wn << 6) + (ni << 4) + lq];
#pragma unroll
    for (int mi = 0; mi < 4; ++mi) {
#pragma unroll
      for (int ni = 0; ni < 4; ++ni)
#pragma unroll
        for (int r = 0; r < 4; ++r)
          st[((g << 2) + r) * 72 + (ni << 4) + lq] = f2bf(acc[mi][ni][r] + bs[ni]);
#pragma unroll
      for (int q2 = 0; q2 < 2; ++q2) {
        const int r16 = l & 15, ch = (l >> 4) + (q2 << 2);
        const s8v vv = *(const s8v*)&st[r16 * 72 + (ch << 3)];
        *(s8v*)&((ushort*)Cout)[(size_t)(m0 + (wm << 6) + (mi << 4) + r16) * N
                                + n0 + (wn << 6) + (ch << 3)] = vv;
      }
    }
  } else {
    float* outf = (float*)Cout + (size_t)blockIdx.z * M * N;
#pragma unroll
    for (int ni = 0; ni < 4; ++ni) {
      const int col = n0 + (wn << 6) + (ni << 4) + lq;
      const float bs = (KSPLIT == 1 || blockIdx.z == 0) ? bias[col] : 0.f;
#pragma unroll
      for (int mi = 0; mi < 4; ++mi) {
        const int row = m0 + (wm << 6) + (mi << 4) + (g << 2);
#pragma unroll
        for (int r = 0; r < 4; ++r)
          outf[(size_t)(row + r) * N + col] = acc[mi][ni][r] + bs;
      }
    }
  }
}

// ---------- MoE expert GEMM (pre-gathered A, counted-vmcnt pipeline) --------
__global__ __launch_bounds__(256, 4) void moe_mfma_kernel(
    const ushort* __restrict__ Xg, const ushort* __restrict__ WeT,
    const float* __restrict__ be, const int* __restrict__ lists,
    const int* __restrict__ offs, const int* __restrict__ cnt,
    const int* __restrict__ tb, ushort* __restrict__ inter)
{
  __shared__ __align__(16) ushort Asm[2][4][128][8];
  __shared__ __align__(16) ushort Bsm[2][4][128][8];
  __shared__ int tokL[128];
  const int by = blockIdx.y;
  if (by >= tb[E_]) return;
  int e = 0;
#pragma unroll
  for (int t = 1; t < E_; ++t) if (by >= tb[t]) e = t;
  const int rt = by - tb[e];
  const int base = offs[e] + (rt << 7);
  const int nrows = cnt[e] - (rt << 7);
  const int tid = threadIdx.x;
  if (tid < 128) tokL[tid] = (tid < nrows) ? lists[base + tid] : -1;
  __syncthreads();
  const int w = tid >> 6, l = tid & 63;
  const int lq = l & 15, g = l >> 4;
  const int wm = w >> 1, wn = w & 1;
  const int n0 = blockIdx.x << 7;
  const int r0 = min(base + l, N_ - 1);
  const int r1 = min(base + 64 + l, N_ - 1);
  const ushort* a0 = Xg + (size_t)r0 * H_ + (w << 3);
  const ushort* a1 = Xg + (size_t)r1 * H_ + (w << 3);
  const ushort* Wp = WeT + (size_t)e * I_ * H_;
  const ushort* b0 = Wp + (size_t)(n0 + l) * H_ + (w << 3);
  const ushort* b1 = b0 + (size_t)64 * H_;

  f4 acc[4][4] = {};
#define STAGE_M(tt, buf)                                   \
  { const int kt_ = (tt) << 5;                             \
    gload16(a0 + kt_, &Asm[buf][w][0][0]);                 \
    gload16(a1 + kt_, &Asm[buf][w][64][0]);                \
    gload16(b0 + kt_, &Bsm[buf][w][0][0]);                 \
    gload16(b1 + kt_, &Bsm[buf][w][64][0]); }
  STAGE_M(0, 0);
  STAGE_M(1, 1);
  for (int t = 0; t < 32; ++t) {
    const int cur = t & 1;
    if (t + 1 < 32) { asm volatile("s_waitcnt vmcnt(4)" ::: "memory"); }
    else            { asm volatile("s_waitcnt vmcnt(0)" ::: "memory"); }
    __builtin_amdgcn_s_barrier();
    __builtin_amdgcn_sched_barrier(0);
    s8v af[4], bfv[4];
#pragma unroll
    for (int mi = 0; mi < 4; ++mi)
      af[mi] = *(const s8v*)&Asm[cur][g][(wm << 6) + (mi << 4) + lq][0];
#pragma unroll
    for (int ni = 0; ni < 4; ++ni)
      bfv[ni] = *(const s8v*)&Bsm[cur][g][(wn << 6) + (ni << 4) + lq][0];
    asm volatile("s_waitcnt lgkmcnt(0)" ::: "memory");
    __builtin_amdgcn_sched_barrier(0);
    __builtin_amdgcn_s_barrier();
    __builtin_amdgcn_sched_barrier(0);
    if (t + 2 < 32) STAGE_M(t + 2, cur);
#pragma unroll
    for (int mi = 0; mi < 4; ++mi)
#pragma unroll
      for (int ni = 0; ni < 4; ++ni)
        acc[mi][ni] = __builtin_amdgcn_mfma_f32_16x16x32_bf16(af[mi], bfv[ni], acc[mi][ni], 0, 0, 0);
  }
#undef STAGE_M
  {
    ushort* st = (ushort*)Asm + (size_t)w * (16 * 72);
    float bs[4];
#pragma unroll
    for (int ni = 0; ni < 4; ++ni) bs[ni] = be[(size_t)e * I_ + n0 + (wn << 6) + (ni << 4) + lq];
#pragma unroll
    for (int mi = 0; mi < 4; ++mi) {
#pragma unroll
      for (int ni = 0; ni < 4; ++ni)
#pragma unroll
        for (int r = 0; r < 4; ++r)
          st[((g << 2) + r) * 72 + (ni << 4) + lq] = f2bf(gelu_f(acc[mi][ni][r] + bs[ni]));
#pragma unroll
      for (int q2 = 0; q2 < 2; ++q2) {
        const int r16 = l & 15, ch = (l >> 4) + (q2 << 2);
        const int tok = tokL[(wm << 6) + (mi << 4) + r16];
        if (tok >= 0) {
          const s8v vv = *(const s8v*)&st[r16 * 72 + (ch << 3)];
          *(s8v*)&inter[(size_t)tok * I_ + n0 + (wn << 6) + (ch << 3)] = vv;
        }
      }
    }
  }
}

// ---------- MFMA flash attention ----------
// V staged raw [key][d] (vectorized, conflict-free) then LDS->reg->LDS
// transposed to Vt[d][key]; async register staging of next tile (T14);
// defer-max (T13); setprio around MFMA clusters (T5).
__global__ __launch_bounds__(256) void attn_mfma_kernel(
    const ushort* __restrict__ qkv, ushort* __restrict__ ctx)
{
  __shared__ __align__(16) ushort Ks[64 * 72];      // [key][d]
  __shared__ __align__(16) ushort Vr[64 * 72];      // [key][d] raw
  __shared__ __align__(16) ushort Vt[64 * 72];      // [d][key]
  __shared__ __align__(16) ushort Ps[4][16 * 72];   // per-wave P [q][key]
  const int bid0 = blockIdx.x;
  const int bid  = ((bid0 & 7) << 7) + (bid0 >> 3);   // bijective XCD swizzle
  const int bh = bid >> 5, qt = bid & 31;
  const int b = bh >> 4, h = bh & 15;
  const int tid = threadIdx.x, w = tid >> 6, l = tid & 63;
  const int lq = l & 15, g = l >> 4;
  const size_t bS = (size_t)b * S_;
  const ushort* qb = qkv + bS * QKVLD + h * DH_;
  const ushort* kb = qb + 1024;
  const ushort* vb = qb + 2048;

  s8v qf0, qf1;
  {
    const ushort* qp = qb + (size_t)(qt * 64 + w * 16 + lq) * QKVLD;
    qf0 = *(const s8v*)(qp + (g << 3));
    qf1 = *(const s8v*)(qp + 32 + (g << 3));
  }

  f4 o0 = {0,0,0,0}, o1 = {0,0,0,0}, o2 = {0,0,0,0}, o3 = {0,0,0,0};
  float mrun = -3.0e38f, lrun = 0.f;

  const int skey = tid >> 2;           // staging: key row 0..63
  const int sd   = (tid & 3) << 4;     // staging: d start {0,16,32,48}

  s8v kr0, kr1, vr0, vr1;              // async staging registers
#define ALOAD(t_) {                                                        \
    const ushort* kp_ = kb + (size_t)((t_) * 64 + skey) * QKVLD + sd;      \
    kr0 = *(const s8v*)kp_; kr1 = *(const s8v*)(kp_ + 8);                  \
    const ushort* vp_ = vb + (size_t)((t_) * 64 + skey) * QKVLD + sd;      \
    vr0 = *(const s8v*)vp_; vr1 = *(const s8v*)(vp_ + 8); }
#define AWRITE() {                                                         \
    *(s8v*)&Ks[skey * 72 + sd]     = kr0;                                  \
    *(s8v*)&Ks[skey * 72 + sd + 8] = kr1;                                  \
    *(s8v*)&Vr[skey * 72 + sd]     = vr0;                                  \
    *(s8v*)&Vr[skey * 72 + sd + 8] = vr1; }

  ALOAD(0); AWRITE();
  ALOAD(1);

  for (int kt = 0; kt < 32; ++kt) {
    asm volatile("s_waitcnt lgkmcnt(0)" ::: "memory");
    __builtin_amdgcn_sched_barrier(0);
    __builtin_amdgcn_s_barrier();            // A: tile kt fully in LDS
    __builtin_amdgcn_sched_barrier(0);

    // LDS transpose Vr[key][d] -> Vt[d][key]; this thread: d=l, keys 16w+j
    {
      s8v t0, t1;
#pragma unroll
      for (int j = 0; j < 8; ++j) {
        t0[j] = (short)Vr[(w * 16 + j) * 72 + l];
        t1[j] = (short)Vr[(w * 16 + 8 + j) * 72 + l];
      }
      *(s8v*)&Vt[l * 72 + w * 16]     = t0;
      *(s8v*)&Vt[l * 72 + w * 16 + 8] = t1;
    }

    // QK^T (swapped): lane l holds S[key=st*16+4g+r][query=lq]
    float s[16];
    __builtin_amdgcn_s_setprio(1);
#pragma unroll
    for (int st = 0; st < 4; ++st) {
      f4 acc = {0, 0, 0, 0};
      const s8v ka0 = *(const s8v*)&Ks[(st * 16 + lq) * 72 + (g << 3)];
      const s8v ka1 = *(const s8v*)&Ks[(st * 16 + lq) * 72 + 32 + (g << 3)];
      acc = __builtin_amdgcn_mfma_f32_16x16x32_bf16(ka0, qf0, acc, 0, 0, 0);
      acc = __builtin_amdgcn_mfma_f32_16x16x32_bf16(ka1, qf1, acc, 0, 0, 0);
      s[st * 4 + 0] = acc[0] * 0.125f; s[st * 4 + 1] = acc[1] * 0.125f;
      s[st * 4 + 2] = acc[2] * 0.125f; s[st * 4 + 3] = acc[3] * 0.125f;
    }
    __builtin_amdgcn_s_setprio(0);

    // online softmax with defer-max (THR=8)
    float tmax = s[0];
#pragma unroll
    for (int i = 1; i < 16; ++i) tmax = fmaxf(tmax, s[i]);
    tmax = fmaxf(tmax, __shfl_xor(tmax, 16));
    tmax = fmaxf(tmax, __shfl_xor(tmax, 32));
    if (!__all(tmax - mrun <= 8.f)) {
      const float mnew  = fmaxf(mrun, tmax);
      const float alpha = __expf(mrun - mnew);
      f4 av;
      av[0] = __shfl(alpha, g * 4 + 0); av[1] = __shfl(alpha, g * 4 + 1);
      av[2] = __shfl(alpha, g * 4 + 2); av[3] = __shfl(alpha, g * 4 + 3);
      o0 *= av; o1 *= av; o2 *= av; o3 *= av;
      lrun *= alpha; mrun = mnew;
    }
    float psum = 0.f;
#pragma unroll
    for (int i = 0; i < 16; ++i) { s[i] = __expf(s[i] - mrun); psum += s[i]; }
    psum += __shfl_xor(psum, 16); psum += __shfl_xor(psum, 32);
    lrun += psum;

    // write P to per-wave LDS: Ps[w][query][key]
    {
      ushort* pw = &Ps[w][lq * 72];
#pragma unroll
      for (int st = 0; st < 4; ++st) {
        *(u32*)&pw[st * 16 + g * 4 + 0] = pack_bf2(s[st * 4 + 0], s[st * 4 + 1]);
        *(u32*)&pw[st * 16 + g * 4 + 2] = pack_bf2(s[st * 4 + 2], s[st * 4 + 3]);
      }
    }
    asm volatile("s_waitcnt lgkmcnt(0)" ::: "memory");
    __builtin_amdgcn_sched_barrier(0);
    __builtin_amdgcn_s_barrier();            // B: Vt complete, Ks/Vr reads done
    __builtin_amdgcn_sched_barrier(0);

    // PV: O += P * V
    __builtin_amdgcn_s_setprio(1);
#pragma unroll
    for (int ks = 0; ks < 2; ++ks) {
      const int kof = ks * 32 + (g << 3);
      const s8v pa = *(const s8v*)&Ps[w][lq * 72 + kof];
      const s8v v0 = *(const s8v*)&Vt[( 0 + lq) * 72 + kof];
      const s8v v1 = *(const s8v*)&Vt[(16 + lq) * 72 + kof];
      const s8v v2 = *(const s8v*)&Vt[(32 + lq) * 72 + kof];
      const s8v v3 = *(const s8v*)&Vt[(48 + lq) * 72 + kof];
      o0 = __builtin_amdgcn_mfma_f32_16x16x32_bf16(pa, v0, o0, 0, 0, 0);
      o1 = __builtin_amdgcn_mfma_f32_16x16x32_bf16(pa, v1, o1, 0, 0, 0);
      o2 = __builtin_amdgcn_mfma_f32_16x16x32_bf16(pa, v2, o2, 0, 0, 0);
      o3 = __builtin_amdgcn_mfma_f32_16x16x32_bf16(pa, v3, o3, 0, 0, 0);
    }
    __builtin_amdgcn_s_setprio(0);

    // stage tile kt+1 (regs -> LDS; vmcnt auto-waited on reg use), load kt+2
    if (kt + 1 < 32) AWRITE();
    if (kt + 2 < 32) ALOAD(kt + 2);
  }
#undef ALOAD
#undef AWRITE

  const float inv = 1.f / lrun;
#pragma unroll
  for (int r = 0; r < 4; ++r) {
    const float li = __shfl(inv, g * 4 + r);
    ushort* op = ctx + (bS + (size_t)(qt * 64 + w * 16 + g * 4 + r)) * H_ + h * DH_ + lq;
    op[0]  = f2bf(o0[r] * li);
    op[16] = f2bf(o1[r] * li);
    op[32] = f2bf(o2[r] * li);
    op[48] = f2bf(o3[r] * li);
  }
}

// ---------- P-partial sum + residual add + LayerNorm ----------
template <int P>
__global__ __launch_bounds__(256) void add_ln_kernel(
    const float* __restrict__ a, const float* __restrict__ r,
    const float* __restrict__ g, const float* __restrict__ bta,
    float* __restrict__ out, ushort* __restrict__ ob)
{
  const int row = blockIdx.x, tid = threadIdx.x;
  const size_t base = (size_t)row * H_;
  const float4 xr = *(const float4*)(r + base + (tid << 2));
  float4 x = xr;
#pragma unroll
  for (int pp = 0; pp < P; ++pp) {
    const float4 xa = *(const float4*)(a + (size_t)pp * N_ * H_ + base + (tid << 2));
    x.x += xa.x; x.y += xa.y; x.z += xa.z; x.w += xa.w;
  }
  float s  = x.x + x.y + x.z + x.w;
  float ss = x.x * x.x + x.y * x.y + x.z * x.z + x.w * x.w;
#pragma unroll
  for (int off = 1; off < 64; off <<= 1) { s += __shfl_xor(s, off); ss += __shfl_xor(ss, off); }
  __shared__ float red[8];
  const int w = tid >> 6, ln = tid & 63;
  if (ln == 0) { red[w] = s; red[4 + w] = ss; }
  __syncthreads();
  const float S  = red[0] + red[1] + red[2] + red[3];
  const float SS = red[4] + red[5] + red[6] + red[7];
  const float mu  = S * (1.f / 1024.f);
  const float var = fmaxf(SS * (1.f / 1024.f) - mu * mu, 0.f);
  const float inv = rsqrtf(var + LN_EPS);
  const float4 gg = *(const float4*)&g[tid << 2];
  const float4 bb = *(const float4*)&bta[tid << 2];
  float4 y;
  y.x = (x.x - mu) * inv * gg.x + bb.x;
  y.y = (x.y - mu) * inv * gg.y + bb.y;
  y.z = (x.z - mu) * inv * gg.z + bb.z;
  y.w = (x.w - mu) * inv * gg.w + bb.w;
  *(float4*)&out[base + (tid << 2)] = y;
  if (ob) {
    ushort4 u;
    u.x = f2bf(y.x); u.y = f2bf(y.y); u.z = f2bf(y.z); u.w = f2bf(y.w);
    *(ushort4*)&ob[base + (tid << 2)] = u;
  }
}

// ---------- router ----------
__global__ __launch_bounds__(64) void router_kernel(
    const float* __restrict__ x, const float* __restrict__ rw,
    int* __restrict__ idx, int* __restrict__ cnt)
{
  const int t = blockIdx.x, lane = threadIdx.x;
  float acc[8] = {0.f};
  for (int c = 0; c < H_; c += 64) {
    const float xv = x[(size_t)t * H_ + c + lane];
    const float* wr = rw + (size_t)(c + lane) * E_;
    const float4 w0 = *(const float4*)wr;
    const float4 w1 = *(const float4*)(wr + 4);
    acc[0] += xv * w0.x; acc[1] += xv * w0.y; acc[2] += xv * w0.z; acc[3] += xv * w0.w;
    acc[4] += xv * w1.x; acc[5] += xv * w1.y; acc[6] += xv * w1.z; acc[7] += xv * w1.w;
  }
#pragma unroll
  for (int e = 0; e < E_; ++e) {
    float s = acc[e];
#pragma unroll
    for (int off = 1; off < 64; off <<= 1) s += __shfl_xor(s, off);
    acc[e] = s;
  }
  if (lane == 0) {
    int be_ = 0; float bv = acc[0];
#pragma unroll
    for (int e = 1; e < E_; ++e) if (acc[e] > bv) { bv = acc[e]; be_ = e; }
    idx[t] = be_;
    atomicAdd(&cnt[be_], 1);
  }
}

__global__ void init_kernel(int* cnt) { if (threadIdx.x < E_) cnt[threadIdx.x] = 0; }

__global__ void scan_kernel(const int* __restrict__ cnt, int* __restrict__ offs,
                            int* __restrict__ cursor, int* __restrict__ tb)
{
  int o = 0, tt = 0;
  for (int e = 0; e < E_; ++e) {
    offs[e] = o; cursor[e] = o; tb[e] = tt;
    o += cnt[e]; tt += (cnt[e] + 127) >> 7;
  }
  tb[E_] = tt;
}

__global__ __launch_bounds__(256) void scatter_kernel(
    const int* __restrict__ idx, int* __restrict__ cursor, int* __restrict__ lists)
{
  const int t = blockIdx.x * 256 + threadIdx.x;
  if (t < N_) {
    const int e = idx[t];
    const int p = atomicAdd(&cursor[e], 1);
    lists[p] = t;
  }
}

// ---------- launch ----------
extern "C" void kernel_launch(void* const* d_in, const int* in_sizes, int n_in,
                              void* d_out, int out_size, void* d_ws, size_t ws_size,
                              hipStream_t stream) {
  const float* x   = (const float*)d_in[0];
  const float* Wq  = (const float*)d_in[1];
  const float* bq  = (const float*)d_in[2];
  const float* Wk  = (const float*)d_in[3];
  const float* bk  = (const float*)d_in[4];
  const float* Wv  = (const float*)d_in[5];
  const float* bv  = (const float*)d_in[6];
  const float* Wao = (const float*)d_in[7];
  const float* bao = (const float*)d_in[8];
  const float* g1  = (const float*)d_in[9];
  const float* b1  = (const float*)d_in[10];
  const float* rw  = (const float*)d_in[11];
  const float* We  = (const float*)d_in[12];
  const float* be  = (const float*)d_in[13];
  const float* Wo  = (const float*)d_in[14];
  const float* bo  = (const float*)d_in[15];
  const float* g2  = (const float*)d_in[16];
  const float* b2  = (const float*)d_in[17];
  float* out = (float*)d_out;

  char* p = (char*)d_ws;
  int* idx    = (int*)p; p += (size_t)N_ * 4;
  int* cnt    = (int*)p; p += 8 * 4;
  int* offs   = (int*)p; p += 8 * 4;
  int* cursor = (int*)p; p += 8 * 4;
  int* tb     = (int*)p; p += 16 * 4;
  int* lists  = (int*)p; p += (size_t)N_ * 4;
  p = (char*)(((uintptr_t)p + 255) & ~(uintptr_t)255);
  const size_t NH = (size_t)N_ * H_;
  ushort* xb     = (ushort*)p; p += NH * 2;                 // x bf16; reused as Xg
  ushort* qkvb   = (ushort*)p;                              // fused qkv bf16 ...
  float*  woPart = (float*)p;  p += (size_t)N_ * QKVLD * 2; // ... reused: Wo partials x2
  ushort* ctxb   = (ushort*)p; p += NH * 2;                 // attn ctx bf16
  float*  attn   = (float*)p;  p += NH * 4;                 // LN1 out fp32
  ushort* attnb  = (ushort*)p; p += NH * 2;                 // LN1 out bf16
  ushort* interb = (ushort*)p;                              // MoE inter bf16 ...
  float*  aoPart = (float*)p;  p += (size_t)N_ * I_ * 2;    // ... reused: AO partials x2
  ushort* WqkvT  = (ushort*)p; p += (size_t)QKVLD * H_ * 2; // [3072][1024]
  ushort* WaoT   = (ushort*)p; p += (size_t)H_ * H_ * 2;    // [1024][1024]
  ushort* WoT    = (ushort*)p; p += (size_t)H_ * I_ * 2;    // [1024][4096]
  ushort* WeT    = (ushort*)p; p += (size_t)E_ * I_ * H_ * 2; // [8][4096][1024]
  float*  bqkv   = (float*)p;  p += QKVLD * 4;
  ushort* Xg     = xb;                                      // expert-sorted tokens

  const dim3 blk(256);

  init_kernel<<<1, 64, 0, stream>>>(cnt);
  cvt_bf16_kernel<<<(N_ * H_ / 8 + 255) / 256, blk, 0, stream>>>(x, xb, N_ * H_ / 8);
  concat3_kernel<<<QKVLD / 256, blk, 0, stream>>>(bq, bk, bv, bqkv);
  transpose_cvt_kernel<<<dim3(32, 32, 1), blk, 0, stream>>>(Wq, WqkvT, H_, H_);
  transpose_cvt_kernel<<<dim3(32, 32, 1), blk, 0, stream>>>(Wk, WqkvT + (size_t)1024 * H_, H_, H_);
  transpose_cvt_kernel<<<dim3(32, 32, 1), blk, 0, stream>>>(Wv, WqkvT + (size_t)2048 * H_, H_, H_);
  transpose_cvt_kernel<<<dim3(32, 32, 1), blk, 0, stream>>>(Wao, WaoT, H_, H_);
  transpose_cvt_kernel<<<dim3(32, 128, 1), blk, 0, stream>>>(Wo, WoT, I_, H_);
  transpose_cvt_kernel<<<dim3(128, 32, 8), blk, 0, stream>>>(We, WeT, H_, I_);

  gemm_mfma_kernel<true, 1><<<dim3(QKVLD / 128, N_ / 128), blk, 0, stream>>>(
      xb, WqkvT, bqkv, qkvb, N_, QKVLD, H_);
  attn_mfma_kernel<<<1024, blk, 0, stream>>>(qkvb, ctxb);
  gemm_mfma_kernel<false, 2><<<dim3(H_ / 128, N_ / 128, 2), blk, 0, stream>>>(
      ctxb, WaoT, bao, aoPart, N_, H_, H_);
  add_ln_kernel<2><<<N_, blk, 0, stream>>>(aoPart, x, g1, b1, attn, attnb);
  router_kernel<<<N_, 64, 0, stream>>>(attn, rw, idx, cnt);
  scan_kernel<<<1, 1, 0, stream>>>(cnt, offs, cursor, tb);
  scatter_kernel<<<N_ / 256, blk, 0, stream>>>(idx, cursor, lists);
  gather_kernel<<<N_ / 2, blk, 0, stream>>>(attnb, lists, Xg);
  moe_mfma_kernel<<<dim3(I_ / 128, N_ / 128 + E_), blk, 0, stream>>>(
      Xg, WeT, be, lists, offs, cnt, tb, interb);
  gemm_mfma_kernel<false, 2><<<dim3(H_ / 128, N_ / 128, 2), blk, 0, stream>>>(
      interb, WoT, bo, woPart, N_, H_, I_);
  add_ln_kernel<2><<<N_, blk, 0, stream>>>(woPart, attn, g2, b2, out, (ushort*)nullptr);
}